// Round 7
// baseline (171.451 us; speedup 1.0000x reference)
//
#include <hip/hip_runtime.h>
#include <hip/hip_bf16.h>
#include <math.h>

typedef unsigned short u16;
typedef unsigned int   u32;
using bf16x8 = __attribute__((ext_vector_type(8))) short;   // 8 bf16 (4 VGPRs)
using f32x4  = __attribute__((ext_vector_type(4))) float;   // MFMA C/D frag
using f32x16 = __attribute__((ext_vector_type(16))) float;  // 32x32 C/D frag
using u32v4  = __attribute__((ext_vector_type(4))) u32;

#define TE 256
#define TH 8
#define TS 2048
#define TB 4
#define NTOK 8192
// (1/sqrt(32)) * log2(e): folded into Q so softmax is pure exp2
#define QSCALE 0.2550120651552454f
#define EXP2(x) __builtin_amdgcn_exp2f(x)

__device__ __forceinline__ void async16(const u16* g, u16* l) {
    __builtin_amdgcn_global_load_lds(
        (const __attribute__((address_space(1))) u32*)g,
        (__attribute__((address_space(3))) u32*)l, 16, 0, 0);
}
// pack 2 floats -> 2 bf16 (round-half-up): 2 adds + v_perm
__device__ __forceinline__ u32 pkbf(float a, float b) {
    u32 ua = __float_as_uint(a) + 0x8000u;
    u32 ub = __float_as_uint(b) + 0x8000u;
    return __builtin_amdgcn_perm(ub, ua, 0x07060302u);  // [ub.b3 ub.b2 ua.b3 ua.b2]
}
__device__ __forceinline__ u16 bf1(float a) {
    return (u16)((__float_as_uint(a) + 0x8000u) >> 16);
}
// counted vmcnt wait (T4): leave N loads in flight across the barrier
template<int N> __device__ __forceinline__ void waitv() {
    if constexpr (N == 0)      asm volatile("s_waitcnt vmcnt(0)" ::: "memory");
    else if constexpr (N == 2) asm volatile("s_waitcnt vmcnt(2)" ::: "memory");
    else                       asm volatile("s_waitcnt vmcnt(4)" ::: "memory");
}

// ---------------- LayerNorm body: one wave per row, bf16 output ------------
__device__ __forceinline__ void ln_body(const float* __restrict__ in,
        u16* __restrict__ out, const float* __restrict__ gamma,
        const float* __restrict__ beta, int rowblk) {
    int row  = rowblk * 4 + (threadIdx.x >> 6);
    int lane = threadIdx.x & 63;
    float4 v = ((const float4*)(in + (size_t)row * TE))[lane];
    float s  = v.x + v.y + v.z + v.w;
    float s2 = v.x*v.x + v.y*v.y + v.z*v.z + v.w*v.w;
    #pragma unroll
    for (int off = 32; off > 0; off >>= 1) {
        s  += __shfl_down(s,  off, 64);
        s2 += __shfl_down(s2, off, 64);
    }
    s  = __shfl(s,  0, 64);
    s2 = __shfl(s2, 0, 64);
    float mu = s * (1.f / TE);
    float rs = rsqrtf(s2 * (1.f / TE) - mu * mu + 1e-5f);
    float4 g = ((const float4*)gamma)[lane];
    float4 b = ((const float4*)beta )[lane];
    u32 lo = pkbf((v.x - mu) * rs * g.x + b.x, (v.y - mu) * rs * g.y + b.y);
    u32 hi = pkbf((v.z - mu) * rs * g.z + b.z, (v.w - mu) * rs * g.w + b.w);
    ((uint2*)(out + (size_t)row * TE))[lane] = make_uint2(lo, hi);
}

__global__ __launch_bounds__(256) void ln_bf(const float* __restrict__ in,
        u16* __restrict__ out, const float* __restrict__ gamma,
        const float* __restrict__ beta) {
    ln_body(in, out, gamma, beta, blockIdx.x);
}

// ---- prep: weights fp32->bf16 (768 blocks) + LN1 (2048 blocks) ------------
// w_in/w_out stay row-major.  w1/w2 are written FRAGMENT-ORDERED for the
// fused FFN kernel (A-operand MFMA frags, 1KB per (tile,k-slice) so the FFN
// reads them as fully-coalesced wave loads):
//   w1[f][k]: ft=f>>5 fr=f&31 kt=k>>4 hi=(k>>3)&1 j=k&7
//     -> u16 idx = ft*8192 + kt*512 + hi*256 + fr*8 + j
//   w2[e][c]: ft=c>>5 kt2=(c>>4)&1 hi=(c>>3)&1 j=c&7 et=e>>5 er=e&31
//     -> u16 idx = ft*8192 + kt2*4096 + et*512 + hi*256 + er*8 + j
__global__ __launch_bounds__(256) void prep(const float* __restrict__ w_in, u16* wib,
        const float* __restrict__ w_out, u16* wob, const float* __restrict__ w1,
        u16* w1f, const float* __restrict__ w2, u16* w2f,
        const float* __restrict__ src, u16* __restrict__ xb,
        const float* __restrict__ g1, const float* __restrict__ be1) {
    if (blockIdx.x < 768) {
        int i = (blockIdx.x * 256 + threadIdx.x) * 4;
        if (i < 196608) {
            float4 v = *(const float4*)(w_in + i);
            *(uint2*)(wib + i) = make_uint2(pkbf(v.x, v.y), pkbf(v.z, v.w));
        } else if (i < 262144) {
            int k = i - 196608;
            float4 v = *(const float4*)(w_out + k);
            *(uint2*)(wob + k) = make_uint2(pkbf(v.x, v.y), pkbf(v.z, v.w));
        } else if (i < 524288) {
            int k = i - 262144;
            int f = k >> 8, c = k & 255;
            int ft = f >> 5, fr = f & 31, kt = c >> 4, hi = (c >> 3) & 1, j = c & 7;
            float4 v = *(const float4*)(w1 + k);
            *(uint2*)(w1f + ft * 8192 + kt * 512 + hi * 256 + fr * 8 + j) =
                make_uint2(pkbf(v.x, v.y), pkbf(v.z, v.w));
        } else {
            int k = i - 524288;
            int e = k >> 10, c = k & 1023;
            int ft = c >> 5, kt2 = (c >> 4) & 1, hi = (c >> 3) & 1, j = c & 7;
            int et = e >> 5, er = e & 31;
            float4 v = *(const float4*)(w2 + k);
            *(uint2*)(w2f + ft * 8192 + kt2 * 4096 + et * 512 + hi * 256 + er * 8 + j) =
                make_uint2(pkbf(v.x, v.y), pkbf(v.z, v.w));
        }
    } else {
        ln_body(src, xb, g1, be1, blockIdx.x - 768);
    }
}

// ------------------- MFMA GEMM: C[N,M] = A[N,K] @ W[M,K]^T -----------------
// Counted-vmcnt software pipeline (T3+T4): BK=32 stages, 3-buffer LDS ring,
// ONE raw s_barrier per stage, s_waitcnt vmcnt(L) (never 0 in steady state).
// BM=BN=128: 4 waves x (64tok x 64feat). BM=BN=64: 4 waves x (32tok x 32feat)
// Operands swapped (D rows=feat, cols=tok) -> lane holds 4 consecutive feats.
// EPI: 0=QKV: feat<256 -> Q bf16 [tok][256] (qscaled); 256..511 -> K frag-
// ordered [bh][tile][frag][hi][lq][8] (Kf = bias); >=512 -> V frag-ordered
// same layout (Vf = R).  1=fp32 +residual.
template<int K, int BM, int EPI>
__global__ __launch_bounds__(256) void mgemm(const u16* __restrict__ A,
        const u16* __restrict__ W, const float* __restrict__ bias,
        const float* __restrict__ R, float* __restrict__ Cf,
        u16* __restrict__ Cb, int M) {
    constexpr int BN = BM;                       // square tiles
    constexpr int NS = K / 32;                   // pipeline stages
    constexpr int L  = (BM == 128) ? 4 : 2;      // async16 per thread / stage
    __shared__ u16 Al[3][BM * 32];
    __shared__ u16 Wl[3][BN * 32];
    const int tid = threadIdx.x, w = tid >> 6, l = tid & 63;
    const int n0 = blockIdx.y * BM;              // token base
    const int m0 = blockIdx.x * BN;              // feat base
    constexpr int NT = (BM == 128) ? 4 : 2;      // tok frags / wave
    constexpr int NF = (BM == 128) ? 4 : 2;      // feat frags / wave
    const int tw = (w & 1) * NT * 16;
    const int fw = (w >> 1) * NF * 16;
    const int fr = l & 15, fq = l >> 4;
    const int sr = l >> 2, sc = (l & 3) * 8;
    f32x4 acc[NT][NF];
    #pragma unroll
    for (int t = 0; t < NT; t++)
        #pragma unroll
        for (int f = 0; f < NF; f++)
            #pragma unroll
            for (int r = 0; r < 4; r++) acc[t][f][r] = 0.f;

    auto stage = [&](int s, int buf) {
        const int kc = s * 32;
        if constexpr (BM == 128) {
            #pragma unroll
            for (int c = 0; c < 2; c++) {
                const int rr = (w * 2 + c) * 16 + sr;
                async16(A + (size_t)(n0 + rr) * K + kc + sc, &Al[buf][(w * 2 + c) * 512]);
                async16(W + (size_t)(m0 + rr) * K + kc + sc, &Wl[buf][(w * 2 + c) * 512]);
            }
        } else {
            const int rr = w * 16 + sr;
            async16(A + (size_t)(n0 + rr) * K + kc + sc, &Al[buf][w * 512]);
            async16(W + (size_t)(m0 + rr) * K + kc + sc, &Wl[buf][w * 512]);
        }
    };

    stage(0, 0);                                 // 2 stages in flight
    stage(1, 1);
    #pragma unroll
    for (int s = 0; s < NS; ++s) {
        const int buf = s % 3;
        if (s < NS - 1) waitv<L>();              // stage s landed; s+1 in flight
        else            waitv<0>();              // final stage: drain
        __builtin_amdgcn_s_barrier();
        __builtin_amdgcn_sched_barrier(0);
        if (s + 2 < NS) stage(s + 2, (s + 2) % 3);
        bf16x8 af[NT], wf[NF];
        #pragma unroll
        for (int t = 0; t < NT; t++)
            af[t] = *(const bf16x8*)&Al[buf][(tw + t * 16 + fr) * 32 + fq * 8];
        #pragma unroll
        for (int f = 0; f < NF; f++)
            wf[f] = *(const bf16x8*)&Wl[buf][(fw + f * 16 + fr) * 32 + fq * 8];
        #pragma unroll
        for (int t = 0; t < NT; t++)
            #pragma unroll
            for (int f = 0; f < NF; f++)
                acc[t][f] = __builtin_amdgcn_mfma_f32_16x16x32_bf16(
                    wf[f], af[t], acc[t][f], 0, 0, 0);   // D rows=feat, cols=tok
    }
    // epilogue: lane holds (tok = n0+tw+t*16+fr, feats fb..fb+3)
    #pragma unroll
    for (int t = 0; t < NT; t++) {
        const int tok = n0 + tw + t * 16 + fr;
        #pragma unroll
        for (int f = 0; f < NF; f++) {
            const int fb = m0 + fw + f * 16 + fq * 4;
            f32x4 v = acc[t][f];
            if (EPI == 0) {
                if (fb < 256) {
                    *(uint2*)(Cb + (size_t)tok * 256 + fb) = make_uint2(
                        pkbf(v[0]*QSCALE, v[1]*QSCALE), pkbf(v[2]*QSCALE, v[3]*QSCALE));
                } else if (fb < 512) {
                    // K fragment-ordered: [bh][tile][frag][hi][lq][8]
                    const int hh = (fb - 256) >> 5, dd = (fb - 256) & 31;
                    const int bh = (tok >> 11) * 8 + hh;
                    const int kv = tok & 2047, tile = kv >> 5, lq = kv & 31;
                    const int fg = dd >> 4, hg = (dd >> 3) & 1, j = dd & 7;
                    u16* kp = (u16*)bias +
                        (((((size_t)bh * 64 + tile) * 2 + fg) * 2 + hg) * 32 + lq) * 8 + j;
                    *(uint2*)kp = make_uint2(pkbf(v[0], v[1]), pkbf(v[2], v[3]));
                } else {
                    // V fragment-ordered: row = d, k-chunk = kv-within-tile
                    const int hh = (fb - 512) >> 5, dd = (fb - 512) & 31;
                    const int bh = (tok >> 11) * 8 + hh;
                    const int kv = tok & 2047, tile = kv >> 5, kvr = kv & 31;
                    const int fg = kvr >> 4, hg = (kvr >> 3) & 1, j = kvr & 7;
                    u16* vp = (u16*)R +
                        ((((size_t)bh * 64 + tile) * 2 + fg) * 2 + hg) * 256 +
                        (size_t)dd * 8 + j;
                    vp[0]  = bf1(v[0]);
                    vp[8]  = bf1(v[1]);
                    vp[16] = bf1(v[2]);
                    vp[24] = bf1(v[3]);
                }
            } else {
                float4 r4 = *(const float4*)(R + (size_t)tok * M + fb);
                *(float4*)(Cf + (size_t)tok * M + fb) =
                    make_float4(v[0]+r4.x, v[1]+r4.y, v[2]+r4.z, v[3]+r4.w);
            }
        }
    }
}

// ------------------ fused FFN: out += relu(x2@W1^T+b1)@W2^T + b2 -----------
// Block = 32 tokens, 4 waves, grid 256.  h (32x1024) never leaves the CU:
// stage 1: wave w computes h-tiles gft = w*8..w*8+8 (128 MFMAs) from
// pre-fragmented W1 (1KB coalesced wave-loads) and in-register x2 B-frags;
// bias+relu, then cvt_pk+permlane32_swap converts the C-layout directly to
// PV-style B-frags (identical algebra to attn's P->PV path) stored in a
// 64KB LDS frag array [gft][kt2][lane*16B] (lane-contiguous = conflict-free).
// One __syncthreads.  Stage 2: wave w computes e-tiles w*2..+2 over the full
// K=1024 (128 MFMAs) from LDS h-frags + pre-fragmented W2; epilogue adds
// b2 + residual.  Replaces the 16MB h1b HBM round-trip + a whole dispatch.
__global__ __launch_bounds__(256) void ffn(const u16* __restrict__ x2b,
        const u16* __restrict__ w1f, const float* __restrict__ b1,
        const u16* __restrict__ w2f, const float* __restrict__ b2,
        float* __restrict__ out) {
    __shared__ u16 hl[32 * 2 * 512];           // 64 KB
    const int tid = threadIdx.x, w = tid >> 6, l = tid & 63;
    const int lt = l & 31, hi = l >> 5;
    const int tok0 = blockIdx.x * 32;

    // x2 B-frags: xf[kt] = x2[tok0+lt][kt*16 + hi*8 .. +8]
    const u16* xrow = x2b + (size_t)(tok0 + lt) * 256 + hi * 8;
    bf16x8 xf[16];
    #pragma unroll
    for (int kt = 0; kt < 16; kt++)
        xf[kt] = *(const bf16x8*)(xrow + kt * 16);

    // ---- stage 1: h[32tok][gft*32..+32] for gft = w*8 .. w*8+8 ----
    #pragma unroll 2
    for (int ftl = 0; ftl < 8; ++ftl) {
        const int gft = w * 8 + ftl;
        const u16* wp = w1f + gft * 8192 + l * 8;
        bf16x8 wfr[16];
        #pragma unroll
        for (int kt = 0; kt < 16; kt++)
            wfr[kt] = *(const bf16x8*)(wp + kt * 512);
        f32x16 acc;
        #pragma unroll
        for (int r = 0; r < 16; r++) acc[r] = 0.f;
        #pragma unroll
        for (int kt = 0; kt < 16; kt++)
            acc = __builtin_amdgcn_mfma_f32_32x32x16_bf16(wfr[kt], xf[kt], acc, 0, 0, 0);
        // bias + relu: acc reg r -> feat gft*32 + (r&3) + 8*(r>>2) + 4*hi
        const float* bb = b1 + gft * 32 + hi * 4;
        float4 b0  = *(const float4*)(bb);
        float4 b8  = *(const float4*)(bb + 8);
        float4 b16 = *(const float4*)(bb + 16);
        float4 b24 = *(const float4*)(bb + 24);
        float t[16];
        t[0]  = fmaxf(acc[0]  + b0.x,  0.f); t[1]  = fmaxf(acc[1]  + b0.y,  0.f);
        t[2]  = fmaxf(acc[2]  + b0.z,  0.f); t[3]  = fmaxf(acc[3]  + b0.w,  0.f);
        t[4]  = fmaxf(acc[4]  + b8.x,  0.f); t[5]  = fmaxf(acc[5]  + b8.y,  0.f);
        t[6]  = fmaxf(acc[6]  + b8.z,  0.f); t[7]  = fmaxf(acc[7]  + b8.w,  0.f);
        t[8]  = fmaxf(acc[8]  + b16.x, 0.f); t[9]  = fmaxf(acc[9]  + b16.y, 0.f);
        t[10] = fmaxf(acc[10] + b16.z, 0.f); t[11] = fmaxf(acc[11] + b16.w, 0.f);
        t[12] = fmaxf(acc[12] + b24.x, 0.f); t[13] = fmaxf(acc[13] + b24.y, 0.f);
        t[14] = fmaxf(acc[14] + b24.z, 0.f); t[15] = fmaxf(acc[15] + b24.w, 0.f);
        u32 a[8];
        #pragma unroll
        for (int j = 0; j < 8; j++)
            asm("v_cvt_pk_bf16_f32 %0, %1, %2"
                : "=v"(a[j]) : "v"(t[2*j]), "v"(t[2*j+1]));
        asm("v_permlane32_swap_b32 %0, %1" : "+v"(a[0]), "+v"(a[2]));
        asm("v_permlane32_swap_b32 %0, %1" : "+v"(a[1]), "+v"(a[3]));
        asm("v_permlane32_swap_b32 %0, %1" : "+v"(a[4]), "+v"(a[6]));
        asm("v_permlane32_swap_b32 %0, %1" : "+v"(a[5]), "+v"(a[7]));
        u32v4 t0 = {a[0], a[1], a[2], a[3]};   // h[tok][gft*32 + hi*8 ..+8]
        u32v4 t1 = {a[4], a[5], a[6], a[7]};   // h[tok][gft*32+16 + hi*8 ..+8]
        u16* hp = &hl[(gft * 2) * 512 + l * 8];
        *(u32v4*)hp = t0;
        *(u32v4*)(hp + 512) = t1;
    }
    __syncthreads();
    // ---- stage 2: out e-tiles et = w*2, w*2+1 over full K=1024 ----
    f32x16 o0, o1;
    #pragma unroll
    for (int r = 0; r < 16; r++) { o0[r] = 0.f; o1[r] = 0.f; }
    #pragma unroll 2
    for (int gft = 0; gft < 32; ++gft) {
        #pragma unroll
        for (int kt2 = 0; kt2 < 2; kt2++) {
            bf16x8 hf = *(const bf16x8*)&hl[(gft * 2 + kt2) * 512 + l * 8];
            const u16* w2p = w2f + gft * 8192 + kt2 * 4096 + (w * 2) * 512 + l * 8;
            bf16x8 wa = *(const bf16x8*)w2p;
            bf16x8 wb = *(const bf16x8*)(w2p + 512);
            o0 = __builtin_amdgcn_mfma_f32_32x32x16_bf16(wa, hf, o0, 0, 0, 0);
            o1 = __builtin_amdgcn_mfma_f32_32x32x16_bf16(wb, hf, o1, 0, 0, 0);
        }
    }
    // epilogue: D rows = e (et*32 + (r&3)+8*(r>>2)+4*hi), cols = tok
    const int tok = tok0 + lt;
    float* orow = out + (size_t)tok * 256;
    {
        const int e0 = (w * 2) * 32 + hi * 4;
        #pragma unroll
        for (int g = 0; g < 4; g++) {
            float4 r4 = *(const float4*)(orow + e0 + g * 8);
            float4 b4 = *(const float4*)(b2 + e0 + g * 8);
            *(float4*)(orow + e0 + g * 8) = make_float4(
                o0[4*g] + r4.x + b4.x, o0[4*g+1] + r4.y + b4.y,
                o0[4*g+2] + r4.z + b4.z, o0[4*g+3] + r4.w + b4.w);
        }
    }
    {
        const int e0 = (w * 2 + 1) * 32 + hi * 4;
        #pragma unroll
        for (int g = 0; g < 4; g++) {
            float4 r4 = *(const float4*)(orow + e0 + g * 8);
            float4 b4 = *(const float4*)(b2 + e0 + g * 8);
            *(float4*)(orow + e0 + g * 8) = make_float4(
                o1[4*g] + r4.x + b4.x, o1[4*g+1] + r4.y + b4.y,
                o1[4*g+2] + r4.z + b4.z, o1[4*g+3] + r4.w + b4.w);
        }
    }
}

// ------------- MFMA flash attention, in-register softmax (T12) -------------
// (unchanged from R2/R6 — best measured variant)
__global__ __launch_bounds__(256, 4) void attn_k(const u16* __restrict__ qb,
        const u16* __restrict__ kfb, const u16* __restrict__ vfb,
        u16* __restrict__ attn) {
    const int id = blockIdx.x;                 // 1024 blocks
    const int bh   = (id & 7) * 4 + (id >> 8); // xcd*4 + group
    const int tile = (id >> 3) & 31;           // 64-q tile within bh
    const int b = bh >> 3, h = bh & 7;
    const int tid = threadIdx.x, w = tid >> 6, l = tid & 63;
    const int qw = w & 1, kw = w >> 1;
    const int lq = l & 31, hi = l >> 5;
    const size_t btok = (size_t)b * TS;
    const int q0 = tile * 64 + qw * 32;

    __shared__ float mrg[2304];                // 2 x 64 lanes x 18 f32

    // Q frags: B-op [col=q=l&31][k=d=(l>>5)*8..+8], pre-scaled by QSCALE
    const u16* qrow = qb + (btok + q0 + lq) * 256 + h * 32 + hi * 8;
    bf16x8 qf0 = *(const bf16x8*)qrow;         // d 0..16
    bf16x8 qf1 = *(const bf16x8*)(qrow + 16);  // d 16..32

    f32x16 zf, o;
    #pragma unroll
    for (int r = 0; r < 16; r++) { zf[r] = 0.f; o[r] = 0.f; }
    float ps = 0.f;

    // fragment streams: 1024 u16 per 32-kv tile, lane l owns bytes l*16..+16
    const u16* kp = kfb + ((size_t)bh * 64 + kw * 32) * 1024 + l * 8;
    const u16* vp = vfb + ((size_t)bh * 64 + kw * 32) * 1024 + l * 8;
    bf16x8 k0 = *(const bf16x8*)kp;
    bf16x8 k1 = *(const bf16x8*)(kp + 512);
    bf16x8 v0 = *(const bf16x8*)vp;
    bf16x8 v1 = *(const bf16x8*)(vp + 512);

    #pragma unroll 2
    for (int it = 0; it < 32; ++it) {
        kp += 1024; vp += 1024;
        // prefetch next tile (last iter reads 1 tile past end -> in-ws, unused)
        bf16x8 nk0 = *(const bf16x8*)kp;
        bf16x8 nk1 = *(const bf16x8*)(kp + 512);
        bf16x8 nv0 = *(const bf16x8*)vp;
        bf16x8 nv1 = *(const bf16x8*)(vp + 512);
        // S[kv][q] (col=q): two chained MFMAs cover d=32
        f32x16 p = __builtin_amdgcn_mfma_f32_32x32x16_bf16(k0, qf0, zf, 0, 0, 0);
        p = __builtin_amdgcn_mfma_f32_32x32x16_bf16(k1, qf1, p, 0, 0, 0);
        float e[16];
        #pragma unroll
        for (int r = 0; r < 16; r++) e[r] = EXP2(p[r]);
        ps += ((e[0]+e[1]) + (e[2]+e[3])) + ((e[4]+e[5]) + (e[6]+e[7]))
            + ((e[8]+e[9]) + (e[10]+e[11])) + ((e[12]+e[13]) + (e[14]+e[15]));
        // pack: a[j] = bf16(e[2j]) | bf16(e[2j+1])<<16  (kv-consecutive pairs)
        u32 a[8];
        #pragma unroll
        for (int j = 0; j < 8; j++)
            asm("v_cvt_pk_bf16_f32 %0, %1, %2"
                : "=v"(a[j]) : "v"(e[2*j]), "v"(e[2*j+1]));
        // redistribute across lane halves: (w0,w2)=swap(a0,a2) etc (T12)
        asm("v_permlane32_swap_b32 %0, %1" : "+v"(a[0]), "+v"(a[2]));
        asm("v_permlane32_swap_b32 %0, %1" : "+v"(a[1]), "+v"(a[3]));
        asm("v_permlane32_swap_b32 %0, %1" : "+v"(a[4]), "+v"(a[6]));
        asm("v_permlane32_swap_b32 %0, %1" : "+v"(a[5]), "+v"(a[7]));
        u32v4 t0 = {a[0], a[1], a[2], a[3]};   // P^T[q][kv0+hi*8 .. +8]
        u32v4 t1 = {a[4], a[5], a[6], a[7]};   // P^T[q][kv0+16+hi*8 .. +8]
        bf16x8 pf0 = __builtin_bit_cast(bf16x8, t0);
        bf16x8 pf1 = __builtin_bit_cast(bf16x8, t1);
        // O^T[d][q] += V^T * P^T
        o = __builtin_amdgcn_mfma_f32_32x32x16_bf16(v0, pf0, o, 0, 0, 0);
        o = __builtin_amdgcn_mfma_f32_32x32x16_bf16(v1, pf1, o, 0, 0, 0);
        k0 = nk0; k1 = nk1; v0 = nv0; v1 = nv1;
    }
    // lane l and l+32 (same q) cover complementary kv rows -> full half-sum
    ps += __shfl_xor(ps, 32, 64);

    // merge the two kv halves: kw=1 dumps (o, ps); kw=0 adds + stores
    if (kw == 1) {
        float* d = mrg + (qw * 64 + l) * 18;
        #pragma unroll
        for (int r = 0; r < 16; r++) d[r] = o[r];
        d[16] = ps;
    }
    __syncthreads();
    if (kw == 0) {
        const float* d = mrg + (qw * 64 + l) * 18;
        #pragma unroll
        for (int r = 0; r < 16; r++) o[r] += d[r];
        ps += d[16];
        float inv = 1.f / ps;
        // o reg r -> d = 8*(r>>2) + 4*hi + (r&3); q = lq
        int tok = (int)btok + q0 + lq;
        u16* orow = attn + (size_t)tok * 256 + h * 32 + hi * 4;
        #pragma unroll
        for (int g = 0; g < 4; g++)
            *(uint2*)(orow + g * 8) = make_uint2(
                pkbf(o[4*g]*inv, o[4*g+1]*inv), pkbf(o[4*g+2]*inv, o[4*g+3]*inv));
    }
}

extern "C" void kernel_launch(void* const* d_in, const int* in_sizes, int n_in,
                              void* d_out, int out_size, void* d_ws, size_t ws_size,
                              hipStream_t stream) {
    const float* src  = (const float*)d_in[0];
    const float* w_in = (const float*)d_in[1];
    const float* w_out= (const float*)d_in[2];
    const float* w1   = (const float*)d_in[3];
    const float* b1   = (const float*)d_in[4];
    const float* w2   = (const float*)d_in[5];
    const float* b2   = (const float*)d_in[6];
    const float* g1   = (const float*)d_in[7];
    const float* be1  = (const float*)d_in[8];
    const float* g2   = (const float*)d_in[9];
    const float* be2  = (const float*)d_in[10];
    float* out = (float*)d_out;

    u16* xb    = (u16*)d_ws;                       // [0, 4MB)    8192 x 256
    u16* qb    = xb + (size_t)NTOK * 256;          // [4, 8MB)    8192 x 256 Q
    u16* kfbuf = qb + (size_t)NTOK * 256;          // [8, 12MB)   K frags
    u16* vfbuf = kfbuf + (size_t)32 * 64 * 1024;   // [12, 16MB)  V frags
    u16* attnb = xb;                               // reuse (xb dead after G2)
    u16* x2b   = (u16*)((char*)d_ws + (size_t)NTOK * 1024 * 2);
    u16* wib   = x2b + (size_t)NTOK * 256;
    u16* wob   = wib + 768 * 256;
    u16* w1fb  = wob + 256 * 256;                  // W1 frags (512 KB)
    u16* w2fb  = w1fb + 1024 * 256;                // W2 frags (512 KB)

    // 1. weights -> bf16 (w1/w2 fragment-ordered)  +  xb = LN1(src)
    prep<<<768 + NTOK / 4, 256, 0, stream>>>(
        w_in, wib, w_out, wob, w1, w1fb, w2, w2fb, src, xb, g1, be1);
    // 2. qb = Q (scaled), kfbuf/vfbuf = K,V fragment-ordered  (= xb @ w_in^T)
    mgemm<256, 128, 0><<<dim3(6, 64), 256, 0, stream>>>(
        xb, wib, (const float*)kfbuf, (const float*)vfbuf, nullptr, qb, 768);
    // 3. attnb = flash-attention(qb, kfbuf, vfbuf)
    attn_k<<<dim3(1024), 256, 0, stream>>>(qb, kfbuf, vfbuf, attnb);
    // 4. out = src + attnb @ w_out^T (fp32)
    mgemm<256, 64, 1><<<dim3(4, 128), 256, 0, stream>>>(
        attnb, wob, nullptr, src, out, nullptr, 256);
    // 5. x2b = LN2(out) -> bf16
    ln_bf<<<NTOK / 4, 256, 0, stream>>>(out, x2b, g2, be2);
    // 6. out += relu(x2b @ w1^T + b1) @ w2^T + b2   (fused, h stays on-chip)
    ffn<<<256, 256, 0, stream>>>(x2b, w1fb, b1, w2fb, b2, out);
}

// Round 8
// 163.177 us; speedup vs baseline: 1.0507x; 1.0507x over previous
//
#include <hip/hip_runtime.h>
#include <hip/hip_bf16.h>
#include <math.h>

typedef unsigned short u16;
typedef unsigned int   u32;
using bf16x8 = __attribute__((ext_vector_type(8))) short;   // 8 bf16 (4 VGPRs)
using f32x4  = __attribute__((ext_vector_type(4))) float;   // MFMA C/D frag
using f32x16 = __attribute__((ext_vector_type(16))) float;  // 32x32 C/D frag
using u32v4  = __attribute__((ext_vector_type(4))) u32;

#define TE 256
#define TH 8
#define TS 2048
#define TB 4
#define NTOK 8192
// (1/sqrt(32)) * log2(e): folded into Q so softmax is pure exp2
#define QSCALE 0.2550120651552454f
#define EXP2(x) __builtin_amdgcn_exp2f(x)

__device__ __forceinline__ void async16(const u16* g, u16* l) {
    __builtin_amdgcn_global_load_lds(
        (const __attribute__((address_space(1))) u32*)g,
        (__attribute__((address_space(3))) u32*)l, 16, 0, 0);
}
// pack 2 floats -> 2 bf16 (round-half-up): 2 adds + v_perm
__device__ __forceinline__ u32 pkbf(float a, float b) {
    u32 ua = __float_as_uint(a) + 0x8000u;
    u32 ub = __float_as_uint(b) + 0x8000u;
    return __builtin_amdgcn_perm(ub, ua, 0x07060302u);  // [ub.b3 ub.b2 ua.b3 ua.b2]
}
__device__ __forceinline__ u16 bf1(float a) {
    return (u16)((__float_as_uint(a) + 0x8000u) >> 16);
}
// counted vmcnt wait (T4): leave N loads in flight across the barrier
template<int N> __device__ __forceinline__ void waitv() {
    if constexpr (N == 0)      asm volatile("s_waitcnt vmcnt(0)" ::: "memory");
    else if constexpr (N == 2) asm volatile("s_waitcnt vmcnt(2)" ::: "memory");
    else                       asm volatile("s_waitcnt vmcnt(4)" ::: "memory");
}

// ---------------- LayerNorm: one wave per row, bf16 output -----------------
__global__ __launch_bounds__(256) void ln_bf(const float* __restrict__ in,
        u16* __restrict__ out, const float* __restrict__ gamma,
        const float* __restrict__ beta) {
    int row  = blockIdx.x * 4 + (threadIdx.x >> 6);
    int lane = threadIdx.x & 63;
    float4 v = ((const float4*)(in + (size_t)row * TE))[lane];
    float s  = v.x + v.y + v.z + v.w;
    float s2 = v.x*v.x + v.y*v.y + v.z*v.z + v.w*v.w;
    #pragma unroll
    for (int off = 32; off > 0; off >>= 1) {
        s  += __shfl_down(s,  off, 64);
        s2 += __shfl_down(s2, off, 64);
    }
    s  = __shfl(s,  0, 64);
    s2 = __shfl(s2, 0, 64);
    float mu = s * (1.f / TE);
    float rs = rsqrtf(s2 * (1.f / TE) - mu * mu + 1e-5f);
    float4 g = ((const float4*)gamma)[lane];
    float4 b = ((const float4*)beta )[lane];
    u32 lo = pkbf((v.x - mu) * rs * g.x + b.x, (v.y - mu) * rs * g.y + b.y);
    u32 hi = pkbf((v.z - mu) * rs * g.z + b.z, (v.w - mu) * rs * g.w + b.w);
    ((uint2*)(out + (size_t)row * TE))[lane] = make_uint2(lo, hi);
}

// -------------- convert the 4 weight matrices fp32 -> bf16 -----------------
__global__ __launch_bounds__(256) void convw(const float* __restrict__ s0, u16* d0,
        const float* __restrict__ s1, u16* d1, const float* __restrict__ s2, u16* d2,
        const float* __restrict__ s3, u16* d3) {
    int i = (blockIdx.x * 256 + threadIdx.x) * 4;
    const float* s; u16* d;
    if      (i < 196608) { s = s0; d = d0; }
    else if (i < 262144) { s = s1; d = d1; i -= 196608; }
    else if (i < 524288) { s = s2; d = d2; i -= 262144; }
    else                 { s = s3; d = d3; i -= 524288; }
    float4 v = *(const float4*)(s + i);
    *(uint2*)(d + i) = make_uint2(pkbf(v.x, v.y), pkbf(v.z, v.w));
}

// ------------------- MFMA GEMM: C[N,M] = A[N,K] @ W[M,K]^T -----------------
// Counted-vmcnt software pipeline (T3+T4): BK=32 stages, 3-buffer LDS ring,
// ONE raw s_barrier per stage, s_waitcnt vmcnt(L) (never 0 in steady state)
// so the next stage's global_load_lds ops stay in flight ACROSS the barrier.
// BM=BN=128: 4 waves x (64tok x 64feat). BM=BN=64: 4 waves x (32tok x 32feat)
// BM=64 ring = 24 KB -> 6 blocks/CU (24 waves/CU) -- used for G2 now too:
// grid 12x128 = 1536 blocks = exactly 6/CU, no dispatch-round tail (the old
// 384-block 128^2 grid ran 1.5 blocks/CU with a half-empty second round).
// Operands swapped (D rows=feat, cols=tok) -> lane holds 4 consecutive feats.
// EPI: 0=QKV: feat<256 -> Q bf16 [tok][256] (qscaled); 256..511 -> K frag-
// ordered [bh][tile][frag][hi][lq][8] (Kf = bias); >=512 -> V frag-ordered
// same layout (Vf = R).  1=fp32 +residual; 2=bf16 relu(acc+bias);
// 3=fp32 acc+bias+residual.
template<int K, int BM, int EPI>
__global__ __launch_bounds__(256) void mgemm(const u16* __restrict__ A,
        const u16* __restrict__ W, const float* __restrict__ bias,
        const float* __restrict__ R, float* __restrict__ Cf,
        u16* __restrict__ Cb, int M) {
    constexpr int BN = BM;                       // square tiles
    constexpr int NS = K / 32;                   // pipeline stages
    constexpr int L  = (BM == 128) ? 4 : 2;      // async16 per thread / stage
    __shared__ u16 Al[3][BM * 32];
    __shared__ u16 Wl[3][BN * 32];
    const int tid = threadIdx.x, w = tid >> 6, l = tid & 63;
    const int n0 = blockIdx.y * BM;              // token base
    const int m0 = blockIdx.x * BN;              // feat base
    constexpr int NT = (BM == 128) ? 4 : 2;      // tok frags / wave
    constexpr int NF = (BM == 128) ? 4 : 2;      // feat frags / wave
    const int tw = (w & 1) * NT * 16;
    const int fw = (w >> 1) * NF * 16;
    const int fr = l & 15, fq = l >> 4;
    const int sr = l >> 2, sc = (l & 3) * 8;
    f32x4 acc[NT][NF];
    #pragma unroll
    for (int t = 0; t < NT; t++)
        #pragma unroll
        for (int f = 0; f < NF; f++)
            #pragma unroll
            for (int r = 0; r < 4; r++) acc[t][f][r] = 0.f;

    auto stage = [&](int s, int buf) {
        const int kc = s * 32;
        if constexpr (BM == 128) {
            #pragma unroll
            for (int c = 0; c < 2; c++) {
                const int rr = (w * 2 + c) * 16 + sr;
                async16(A + (size_t)(n0 + rr) * K + kc + sc, &Al[buf][(w * 2 + c) * 512]);
                async16(W + (size_t)(m0 + rr) * K + kc + sc, &Wl[buf][(w * 2 + c) * 512]);
            }
        } else {
            const int rr = w * 16 + sr;
            async16(A + (size_t)(n0 + rr) * K + kc + sc, &Al[buf][w * 512]);
            async16(W + (size_t)(m0 + rr) * K + kc + sc, &Wl[buf][w * 512]);
        }
    };

    stage(0, 0);                                 // 2 stages in flight
    stage(1, 1);
    #pragma unroll
    for (int s = 0; s < NS; ++s) {
        const int buf = s % 3;
        if (s < NS - 1) waitv<L>();              // stage s landed; s+1 in flight
        else            waitv<0>();              // final stage: drain
        __builtin_amdgcn_s_barrier();
        __builtin_amdgcn_sched_barrier(0);
        if (s + 2 < NS) stage(s + 2, (s + 2) % 3);
        bf16x8 af[NT], wf[NF];
        #pragma unroll
        for (int t = 0; t < NT; t++)
            af[t] = *(const bf16x8*)&Al[buf][(tw + t * 16 + fr) * 32 + fq * 8];
        #pragma unroll
        for (int f = 0; f < NF; f++)
            wf[f] = *(const bf16x8*)&Wl[buf][(fw + f * 16 + fr) * 32 + fq * 8];
        #pragma unroll
        for (int t = 0; t < NT; t++)
            #pragma unroll
            for (int f = 0; f < NF; f++)
                acc[t][f] = __builtin_amdgcn_mfma_f32_16x16x32_bf16(
                    wf[f], af[t], acc[t][f], 0, 0, 0);   // D rows=feat, cols=tok
    }
    // epilogue: lane holds (tok = n0+tw+t*16+fr, feats fb..fb+3)
    #pragma unroll
    for (int t = 0; t < NT; t++) {
        const int tok = n0 + tw + t * 16 + fr;
        #pragma unroll
        for (int f = 0; f < NF; f++) {
            const int fb = m0 + fw + f * 16 + fq * 4;
            f32x4 v = acc[t][f];
            if (EPI == 0) {
                if (fb < 256) {
                    *(uint2*)(Cb + (size_t)tok * 256 + fb) = make_uint2(
                        pkbf(v[0]*QSCALE, v[1]*QSCALE), pkbf(v[2]*QSCALE, v[3]*QSCALE));
                } else if (fb < 512) {
                    // K fragment-ordered: [bh][tile][frag][hi][lq][8]
                    const int hh = (fb - 256) >> 5, dd = (fb - 256) & 31;
                    const int bh = (tok >> 11) * 8 + hh;
                    const int kv = tok & 2047, tile = kv >> 5, lq = kv & 31;
                    const int fg = dd >> 4, hg = (dd >> 3) & 1, j = dd & 7;
                    u16* kp = (u16*)bias +
                        (((((size_t)bh * 64 + tile) * 2 + fg) * 2 + hg) * 32 + lq) * 8 + j;
                    *(uint2*)kp = make_uint2(pkbf(v[0], v[1]), pkbf(v[2], v[3]));
                } else {
                    // V fragment-ordered: row = d, k-chunk = kv-within-tile
                    const int hh = (fb - 512) >> 5, dd = (fb - 512) & 31;
                    const int bh = (tok >> 11) * 8 + hh;
                    const int kv = tok & 2047, tile = kv >> 5, kvr = kv & 31;
                    const int fg = kvr >> 4, hg = (kvr >> 3) & 1, j = kvr & 7;
                    u16* vp = (u16*)R +
                        ((((size_t)bh * 64 + tile) * 2 + fg) * 2 + hg) * 256 +
                        (size_t)dd * 8 + j;
                    vp[0]  = bf1(v[0]);
                    vp[8]  = bf1(v[1]);
                    vp[16] = bf1(v[2]);
                    vp[24] = bf1(v[3]);
                }
            } else if (EPI == 1) {
                float4 r4 = *(const float4*)(R + (size_t)tok * M + fb);
                *(float4*)(Cf + (size_t)tok * M + fb) =
                    make_float4(v[0]+r4.x, v[1]+r4.y, v[2]+r4.z, v[3]+r4.w);
            } else if (EPI == 2) {
                float4 b4 = *(const float4*)(bias + fb);
                *(uint2*)(Cb + (size_t)tok * M + fb) = make_uint2(
                    pkbf(fmaxf(v[0]+b4.x, 0.f), fmaxf(v[1]+b4.y, 0.f)),
                    pkbf(fmaxf(v[2]+b4.z, 0.f), fmaxf(v[3]+b4.w, 0.f)));
            } else {
                float4 b4 = *(const float4*)(bias + fb);
                float4 r4 = *(const float4*)(R + (size_t)tok * M + fb);
                *(float4*)(Cf + (size_t)tok * M + fb) = make_float4(
                    v[0]+b4.x+r4.x, v[1]+b4.y+r4.y, v[2]+b4.z+r4.z, v[3]+b4.w+r4.w);
            }
        }
    }
}

// ------------- MFMA flash attention, in-register softmax (T12) -------------
// (unchanged from R2/R6 — best measured variant)
__global__ __launch_bounds__(256, 4) void attn_k(const u16* __restrict__ qb,
        const u16* __restrict__ kfb, const u16* __restrict__ vfb,
        u16* __restrict__ attn) {
    const int id = blockIdx.x;                 // 1024 blocks
    const int bh   = (id & 7) * 4 + (id >> 8); // xcd*4 + group
    const int tile = (id >> 3) & 31;           // 64-q tile within bh
    const int b = bh >> 3, h = bh & 7;
    const int tid = threadIdx.x, w = tid >> 6, l = tid & 63;
    const int qw = w & 1, kw = w >> 1;
    const int lq = l & 31, hi = l >> 5;
    const size_t btok = (size_t)b * TS;
    const int q0 = tile * 64 + qw * 32;

    __shared__ float mrg[2304];                // 2 x 64 lanes x 18 f32

    // Q frags: B-op [col=q=l&31][k=d=(l>>5)*8..+8], pre-scaled by QSCALE
    const u16* qrow = qb + (btok + q0 + lq) * 256 + h * 32 + hi * 8;
    bf16x8 qf0 = *(const bf16x8*)qrow;         // d 0..16
    bf16x8 qf1 = *(const bf16x8*)(qrow + 16);  // d 16..32

    f32x16 zf, o;
    #pragma unroll
    for (int r = 0; r < 16; r++) { zf[r] = 0.f; o[r] = 0.f; }
    float ps = 0.f;

    // fragment streams: 1024 u16 per 32-kv tile, lane l owns bytes l*16..+16
    const u16* kp = kfb + ((size_t)bh * 64 + kw * 32) * 1024 + l * 8;
    const u16* vp = vfb + ((size_t)bh * 64 + kw * 32) * 1024 + l * 8;
    bf16x8 k0 = *(const bf16x8*)kp;
    bf16x8 k1 = *(const bf16x8*)(kp + 512);
    bf16x8 v0 = *(const bf16x8*)vp;
    bf16x8 v1 = *(const bf16x8*)(vp + 512);

    #pragma unroll 2
    for (int it = 0; it < 32; ++it) {
        kp += 1024; vp += 1024;
        // prefetch next tile (last iter reads 1 tile past end -> in-ws, unused)
        bf16x8 nk0 = *(const bf16x8*)kp;
        bf16x8 nk1 = *(const bf16x8*)(kp + 512);
        bf16x8 nv0 = *(const bf16x8*)vp;
        bf16x8 nv1 = *(const bf16x8*)(vp + 512);
        // S[kv][q] (col=q): two chained MFMAs cover d=32
        f32x16 p = __builtin_amdgcn_mfma_f32_32x32x16_bf16(k0, qf0, zf, 0, 0, 0);
        p = __builtin_amdgcn_mfma_f32_32x32x16_bf16(k1, qf1, p, 0, 0, 0);
        float e[16];
        #pragma unroll
        for (int r = 0; r < 16; r++) e[r] = EXP2(p[r]);
        ps += ((e[0]+e[1]) + (e[2]+e[3])) + ((e[4]+e[5]) + (e[6]+e[7]))
            + ((e[8]+e[9]) + (e[10]+e[11])) + ((e[12]+e[13]) + (e[14]+e[15]));
        // pack: a[j] = bf16(e[2j]) | bf16(e[2j+1])<<16  (kv-consecutive pairs)
        u32 a[8];
        #pragma unroll
        for (int j = 0; j < 8; j++)
            asm("v_cvt_pk_bf16_f32 %0, %1, %2"
                : "=v"(a[j]) : "v"(e[2*j]), "v"(e[2*j+1]));
        // redistribute across lane halves: (w0,w2)=swap(a0,a2) etc (T12)
        asm("v_permlane32_swap_b32 %0, %1" : "+v"(a[0]), "+v"(a[2]));
        asm("v_permlane32_swap_b32 %0, %1" : "+v"(a[1]), "+v"(a[3]));
        asm("v_permlane32_swap_b32 %0, %1" : "+v"(a[4]), "+v"(a[6]));
        asm("v_permlane32_swap_b32 %0, %1" : "+v"(a[5]), "+v"(a[7]));
        u32v4 t0 = {a[0], a[1], a[2], a[3]};   // P^T[q][kv0+hi*8 .. +8]
        u32v4 t1 = {a[4], a[5], a[6], a[7]};   // P^T[q][kv0+16+hi*8 .. +8]
        bf16x8 pf0 = __builtin_bit_cast(bf16x8, t0);
        bf16x8 pf1 = __builtin_bit_cast(bf16x8, t1);
        // O^T[d][q] += V^T * P^T
        o = __builtin_amdgcn_mfma_f32_32x32x16_bf16(v0, pf0, o, 0, 0, 0);
        o = __builtin_amdgcn_mfma_f32_32x32x16_bf16(v1, pf1, o, 0, 0, 0);
        k0 = nk0; k1 = nk1; v0 = nv0; v1 = nv1;
    }
    // lane l and l+32 (same q) cover complementary kv rows -> full half-sum
    ps += __shfl_xor(ps, 32, 64);

    // merge the two kv halves: kw=1 dumps (o, ps); kw=0 adds + stores
    if (kw == 1) {
        float* d = mrg + (qw * 64 + l) * 18;
        #pragma unroll
        for (int r = 0; r < 16; r++) d[r] = o[r];
        d[16] = ps;
    }
    __syncthreads();
    if (kw == 0) {
        const float* d = mrg + (qw * 64 + l) * 18;
        #pragma unroll
        for (int r = 0; r < 16; r++) o[r] += d[r];
        ps += d[16];
        float inv = 1.f / ps;
        // o reg r -> d = 8*(r>>2) + 4*hi + (r&3); q = lq
        int tok = (int)btok + q0 + lq;
        u16* orow = attn + (size_t)tok * 256 + h * 32 + hi * 4;
        #pragma unroll
        for (int g = 0; g < 4; g++)
            *(uint2*)(orow + g * 8) = make_uint2(
                pkbf(o[4*g]*inv, o[4*g+1]*inv), pkbf(o[4*g+2]*inv, o[4*g+3]*inv));
    }
}

extern "C" void kernel_launch(void* const* d_in, const int* in_sizes, int n_in,
                              void* d_out, int out_size, void* d_ws, size_t ws_size,
                              hipStream_t stream) {
    const float* src  = (const float*)d_in[0];
    const float* w_in = (const float*)d_in[1];
    const float* w_out= (const float*)d_in[2];
    const float* w1   = (const float*)d_in[3];
    const float* b1   = (const float*)d_in[4];
    const float* w2   = (const float*)d_in[5];
    const float* b2   = (const float*)d_in[6];
    const float* g1   = (const float*)d_in[7];
    const float* be1  = (const float*)d_in[8];
    const float* g2   = (const float*)d_in[9];
    const float* be2  = (const float*)d_in[10];
    float* out = (float*)d_out;

    u16* xb    = (u16*)d_ws;                       // [0, 4MB)    8192 x 256
    u16* qb    = xb + (size_t)NTOK * 256;          // [4, 8MB)    8192 x 256 Q
    u16* kfbuf = qb + (size_t)NTOK * 256;          // [8, 12MB)   K frags
    u16* vfbuf = kfbuf + (size_t)32 * 64 * 1024;   // [12, 16MB)  V frags
    u16* attnb = xb;                               // reuse (xb dead after G2)
    u16* h1b   = (u16*)d_ws;                       // 8192*1024 (after attn GEMMs)
    u16* x2b   = (u16*)((char*)d_ws + (size_t)NTOK * 1024 * 2);
    u16* wib   = x2b + (size_t)NTOK * 256;
    u16* wob   = wib + 768 * 256;
    u16* w1b   = wob + 256 * 256;
    u16* w2b   = w1b + 1024 * 256;

    convw<<<768, 256, 0, stream>>>(w_in, wib, w_out, wob, w1, w1b, w2, w2b);
    // 1. xb = LN1(src) -> bf16
    ln_bf<<<NTOK / 4, 256, 0, stream>>>(src, xb, g1, be1);
    // 2. qb = Q (scaled), kfbuf/vfbuf = K,V fragment-ordered  (= xb @ w_in^T)
    //    64^2 tiles: 1536 blocks = 6/CU exact (no tail; was 384 = 1.5/CU)
    mgemm<256, 64, 0><<<dim3(12, 128), 256, 0, stream>>>(
        xb, wib, (const float*)kfbuf, (const float*)vfbuf, nullptr, qb, 768);
    // 3. attnb = flash-attention(qb, kfbuf, vfbuf)
    attn_k<<<dim3(1024), 256, 0, stream>>>(qb, kfbuf, vfbuf, attnb);
    // 4. out = src + attnb @ w_out^T (fp32)
    mgemm<256, 64, 1><<<dim3(4, 128), 256, 0, stream>>>(
        attnb, wob, nullptr, src, out, nullptr, 256);
    // 5. x2b = LN2(out) -> bf16
    ln_bf<<<NTOK / 4, 256, 0, stream>>>(out, x2b, g2, be2);
    // 6. h1b = relu(x2b @ w1^T + b1) -> bf16
    mgemm<256, 128, 2><<<dim3(8, 64), 256, 0, stream>>>(
        x2b, w1b, b1, nullptr, nullptr, h1b, 1024);
    // 7. out = out + h1b @ w2^T + b2 (fp32)
    mgemm<1024, 64, 3><<<dim3(4, 128), 256, 0, stream>>>(
        h1b, w2b, b2, out, out, nullptr, 256);
}

// Round 9
// 159.574 us; speedup vs baseline: 1.0744x; 1.0226x over previous
//
#include <hip/hip_runtime.h>
#include <hip/hip_bf16.h>
#include <math.h>

typedef unsigned short u16;
typedef unsigned int   u32;
using bf16x8 = __attribute__((ext_vector_type(8))) short;   // 8 bf16 (4 VGPRs)
using f32x4  = __attribute__((ext_vector_type(4))) float;   // MFMA C/D frag
using f32x16 = __attribute__((ext_vector_type(16))) float;  // 32x32 C/D frag
using u32v4  = __attribute__((ext_vector_type(4))) u32;

#define TE 256
#define TH 8
#define TS 2048
#define TB 4
#define NTOK 8192
// (1/sqrt(32)) * log2(e): folded into Q so softmax is pure exp2
#define QSCALE 0.2550120651552454f
#define EXP2(x) __builtin_amdgcn_exp2f(x)

__device__ __forceinline__ void async16(const u16* g, u16* l) {
    __builtin_amdgcn_global_load_lds(
        (const __attribute__((address_space(1))) u32*)g,
        (__attribute__((address_space(3))) u32*)l, 16, 0, 0);
}
// pack 2 floats -> 2 bf16 (round-half-up): 2 adds + v_perm
__device__ __forceinline__ u32 pkbf(float a, float b) {
    u32 ua = __float_as_uint(a) + 0x8000u;
    u32 ub = __float_as_uint(b) + 0x8000u;
    return __builtin_amdgcn_perm(ub, ua, 0x07060302u);  // [ub.b3 ub.b2 ua.b3 ua.b2]
}
__device__ __forceinline__ u16 bf1(float a) {
    return (u16)((__float_as_uint(a) + 0x8000u) >> 16);
}

// ---------------- LayerNorm body: one wave per row, bf16 output ------------
__device__ __forceinline__ void ln_body(const float* __restrict__ in,
        u16* __restrict__ out, const float* __restrict__ gamma,
        const float* __restrict__ beta, int rowblk) {
    int row  = rowblk * 4 + (threadIdx.x >> 6);
    int lane = threadIdx.x & 63;
    float4 v = ((const float4*)(in + (size_t)row * TE))[lane];
    float s  = v.x + v.y + v.z + v.w;
    float s2 = v.x*v.x + v.y*v.y + v.z*v.z + v.w*v.w;
    #pragma unroll
    for (int off = 32; off > 0; off >>= 1) {
        s  += __shfl_down(s,  off, 64);
        s2 += __shfl_down(s2, off, 64);
    }
    s  = __shfl(s,  0, 64);
    s2 = __shfl(s2, 0, 64);
    float mu = s * (1.f / TE);
    float rs = rsqrtf(s2 * (1.f / TE) - mu * mu + 1e-5f);
    float4 g = ((const float4*)gamma)[lane];
    float4 b = ((const float4*)beta )[lane];
    u32 lo = pkbf((v.x - mu) * rs * g.x + b.x, (v.y - mu) * rs * g.y + b.y);
    u32 hi = pkbf((v.z - mu) * rs * g.z + b.z, (v.w - mu) * rs * g.w + b.w);
    ((uint2*)(out + (size_t)row * TE))[lane] = make_uint2(lo, hi);
}

// ---- prep: weight fp32->bf16 conversion (768 blocks) + LN1 (2048 blocks) ---
__global__ __launch_bounds__(256) void prep(const float* __restrict__ s0, u16* d0,
        const float* __restrict__ s1, u16* d1, const float* __restrict__ s2, u16* d2,
        const float* __restrict__ s3, u16* d3, const float* __restrict__ src,
        u16* __restrict__ xb, const float* __restrict__ g1,
        const float* __restrict__ be1) {
    if (blockIdx.x < 768) {
        int i = (blockIdx.x * 256 + threadIdx.x) * 4;
        const float* s; u16* d;
        if      (i < 196608) { s = s0; d = d0; }
        else if (i < 262144) { s = s1; d = d1; i -= 196608; }
        else if (i < 524288) { s = s2; d = d2; i -= 262144; }
        else                 { s = s3; d = d3; i -= 524288; }
        float4 v = *(const float4*)(s + i);
        *(uint2*)(d + i) = make_uint2(pkbf(v.x, v.y), pkbf(v.z, v.w));
    } else {
        ln_body(src, xb, g1, be1, blockIdx.x - 768);
    }
}

// ------------------- MFMA GEMM: C[N,M] = A[N,K] @ W[M,K]^T -----------------
// R2-proven structure: BK=64 staged as two 32-halves per barrier pair.
// BM=BN=128: 4 waves x (64tok x 64feat). BM=BN=64: 4 waves x (32tok x 32feat)
// Operands swapped (D rows=feat, cols=tok) -> lane holds 4 consecutive feats.
// EPI: 0=QKV: feat<256 -> Q bf16 [tok][256] (qscaled); 256..511 -> K frag-
// ordered [bh][tile][frag][hi][lq][8] (Kf = bias); >=512 -> V frag-ordered
// same layout (Vf = R).  2=bf16 relu(acc+bias); 3=fp32 acc+bias+residual.
template<int K, int BM, int EPI>
__global__ __launch_bounds__(256) void mgemm(const u16* __restrict__ A,
        const u16* __restrict__ W, const float* __restrict__ bias,
        const float* __restrict__ R, float* __restrict__ Cf,
        u16* __restrict__ Cb, int M) {
    constexpr int BN = BM;                       // square tiles
    __shared__ u16 Al[2][BM * 32];
    __shared__ u16 Wl[2][BN * 32];
    const int tid = threadIdx.x, w = tid >> 6, l = tid & 63;
    const int n0 = blockIdx.y * BM;              // token base
    const int m0 = blockIdx.x * BN;              // feat base
    constexpr int NT = (BM == 128) ? 4 : 2;      // tok frags / wave
    constexpr int NF = (BM == 128) ? 4 : 2;      // feat frags / wave
    const int tw = (w & 1) * NT * 16;
    const int fw = (w >> 1) * NF * 16;
    const int fr = l & 15, fq = l >> 4;
    const int sr = l >> 2, sc = (l & 3) * 8;
    f32x4 acc[NT][NF];
    #pragma unroll
    for (int t = 0; t < NT; t++)
        #pragma unroll
        for (int f = 0; f < NF; f++)
            #pragma unroll
            for (int r = 0; r < 4; r++) acc[t][f][r] = 0.f;

    for (int k0 = 0; k0 < K; k0 += 64) {
        __syncthreads();
        #pragma unroll
        for (int hh = 0; hh < 2; hh++) {
            const int kc = k0 + hh * 32;
            if (BM == 128) {
                #pragma unroll
                for (int c = 0; c < 2; c++) {
                    int rr = (w * 2 + c) * 16 + sr;
                    async16(A + (size_t)(n0 + rr) * K + kc + sc, &Al[hh][(w * 2 + c) * 512]);
                    async16(W + (size_t)(m0 + rr) * K + kc + sc, &Wl[hh][(w * 2 + c) * 512]);
                }
            } else {
                int rr = w * 16 + sr;
                async16(A + (size_t)(n0 + rr) * K + kc + sc, &Al[hh][w * 512]);
                async16(W + (size_t)(m0 + rr) * K + kc + sc, &Wl[hh][w * 512]);
            }
        }
        __syncthreads();
        #pragma unroll
        for (int hh = 0; hh < 2; hh++) {
            bf16x8 af[NT], wf[NF];
            #pragma unroll
            for (int t = 0; t < NT; t++)
                af[t] = *(const bf16x8*)&Al[hh][(tw + t * 16 + fr) * 32 + fq * 8];
            #pragma unroll
            for (int f = 0; f < NF; f++)
                wf[f] = *(const bf16x8*)&Wl[hh][(fw + f * 16 + fr) * 32 + fq * 8];
            #pragma unroll
            for (int t = 0; t < NT; t++)
                #pragma unroll
                for (int f = 0; f < NF; f++)
                    acc[t][f] = __builtin_amdgcn_mfma_f32_16x16x32_bf16(
                        wf[f], af[t], acc[t][f], 0, 0, 0);   // D rows=feat, cols=tok
        }
    }
    // epilogue: lane holds (tok = n0+tw+t*16+fr, feats fb..fb+3)
    #pragma unroll
    for (int t = 0; t < NT; t++) {
        const int tok = n0 + tw + t * 16 + fr;
        #pragma unroll
        for (int f = 0; f < NF; f++) {
            const int fb = m0 + fw + f * 16 + fq * 4;
            f32x4 v = acc[t][f];
            if (EPI == 0) {
                if (fb < 256) {
                    *(uint2*)(Cb + (size_t)tok * 256 + fb) = make_uint2(
                        pkbf(v[0]*QSCALE, v[1]*QSCALE), pkbf(v[2]*QSCALE, v[3]*QSCALE));
                } else if (fb < 512) {
                    // K fragment-ordered: [bh][tile][frag][hi][lq][8]
                    const int hh = (fb - 256) >> 5, dd = (fb - 256) & 31;
                    const int bh = (tok >> 11) * 8 + hh;
                    const int kv = tok & 2047, tile = kv >> 5, lq = kv & 31;
                    const int fg = dd >> 4, hg = (dd >> 3) & 1, j = dd & 7;
                    u16* kp = (u16*)bias +
                        (((((size_t)bh * 64 + tile) * 2 + fg) * 2 + hg) * 32 + lq) * 8 + j;
                    *(uint2*)kp = make_uint2(pkbf(v[0], v[1]), pkbf(v[2], v[3]));
                } else {
                    // V fragment-ordered: row = d, k-chunk = kv-within-tile
                    const int hh = (fb - 512) >> 5, dd = (fb - 512) & 31;
                    const int bh = (tok >> 11) * 8 + hh;
                    const int kv = tok & 2047, tile = kv >> 5, kvr = kv & 31;
                    const int fg = kvr >> 4, hg = (kvr >> 3) & 1, j = kvr & 7;
                    u16* vp = (u16*)R +
                        ((((size_t)bh * 64 + tile) * 2 + fg) * 2 + hg) * 256 +
                        (size_t)dd * 8 + j;
                    vp[0]  = bf1(v[0]);
                    vp[8]  = bf1(v[1]);
                    vp[16] = bf1(v[2]);
                    vp[24] = bf1(v[3]);
                }
            } else if (EPI == 2) {
                float4 b4 = *(const float4*)(bias + fb);
                *(uint2*)(Cb + (size_t)tok * M + fb) = make_uint2(
                    pkbf(fmaxf(v[0]+b4.x, 0.f), fmaxf(v[1]+b4.y, 0.f)),
                    pkbf(fmaxf(v[2]+b4.z, 0.f), fmaxf(v[3]+b4.w, 0.f)));
            } else {
                float4 b4 = *(const float4*)(bias + fb);
                float4 r4 = *(const float4*)(R + (size_t)tok * M + fb);
                *(float4*)(Cf + (size_t)tok * M + fb) = make_float4(
                    v[0]+b4.x+r4.x, v[1]+b4.y+r4.y, v[2]+b4.z+r4.z, v[3]+b4.w+r4.w);
            }
        }
    }
}

// ---- g4ln: out = src + attnb @ w_out^T, then x2b = LN2(out) (fused) -------
// Block = 32 tokens x all 256 feats (K=256), 8 waves: tg=w&1 (16 tok),
// fg=w>>1 (64 feats).  Epilogue owns complete rows -> LN computed in-block
// from an LDS fp32 tile (row pad 260 breaks bank aliasing).  Saves the
// separate LN2 kernel + its 12 MB round-trip.
__global__ __launch_bounds__(512) void g4ln(const u16* __restrict__ A,
        const u16* __restrict__ W, const float* __restrict__ src,
        float* __restrict__ out, u16* __restrict__ x2b,
        const float* __restrict__ g2, const float* __restrict__ be2) {
    __shared__ __align__(16) char smem[36864];
    u16* Al = (u16*)smem;                  // [2][32*32]
    u16* Wl = (u16*)(smem + 4096);         // [2][256*32]
    const int tid = threadIdx.x, w = tid >> 6, l = tid & 63;
    const int tg = w & 1, fg = w >> 1;
    const int fr = l & 15, fq = l >> 4;
    const int sr = l >> 2, sc = (l & 3) * 8;
    const int n0 = blockIdx.x * 32;
    f32x4 acc[4];
    #pragma unroll
    for (int f = 0; f < 4; f++)
        #pragma unroll
        for (int r = 0; r < 4; r++) acc[f][r] = 0.f;

    auto stage = [&](int st, int buf) {
        const int kc = st * 32;
        const int rr = w * 16 + sr;
        async16(W + (size_t)rr * 256 + kc + sc, &Wl[buf * 8192 + w * 512]);
        async16(W + (size_t)(rr + 128) * 256 + kc + sc, &Wl[buf * 8192 + 4096 + w * 512]);
        if (w < 2) async16(A + (size_t)(n0 + rr) * 256 + kc + sc, &Al[buf * 1024 + w * 512]);
    };

    stage(0, 0);
    __syncthreads();
    #pragma unroll 2
    for (int st = 0; st < 8; ++st) {
        const int buf = st & 1;
        if (st + 1 < 8) stage(st + 1, buf ^ 1);
        bf16x8 af = *(const bf16x8*)&Al[buf * 1024 + (tg * 16 + fr) * 32 + fq * 8];
        bf16x8 wf[4];
        #pragma unroll
        for (int f = 0; f < 4; f++)
            wf[f] = *(const bf16x8*)&Wl[buf * 8192 + (fg * 64 + f * 16 + fr) * 32 + fq * 8];
        #pragma unroll
        for (int f = 0; f < 4; f++)
            acc[f] = __builtin_amdgcn_mfma_f32_16x16x32_bf16(wf[f], af, acc[f], 0, 0, 0);
        __syncthreads();
    }
    // epilogue: residual add, write out, stash rows in LDS, then LN in-block
    float* T = (float*)smem;               // [32][260] f32 (33280 B <= 36864)
    const int tokl = tg * 16 + fr;
    const int tok  = n0 + tokl;
    #pragma unroll
    for (int f = 0; f < 4; ++f) {
        const int fb = fg * 64 + f * 16 + fq * 4;
        float4 s4 = *(const float4*)(src + (size_t)tok * 256 + fb);
        f32x4 v = acc[f];
        float4 o4 = make_float4(v[0]+s4.x, v[1]+s4.y, v[2]+s4.z, v[3]+s4.w);
        *(float4*)(out + (size_t)tok * 256 + fb) = o4;
        *(float4*)&T[tokl * 260 + fb] = o4;
    }
    __syncthreads();
    float4 gg = ((const float4*)g2)[l];
    float4 bb = ((const float4*)be2)[l];
    #pragma unroll
    for (int rr = 0; rr < 4; ++rr) {
        const int r = w * 4 + rr;
        float4 x = *(const float4*)&T[r * 260 + l * 4];
        float s  = x.x + x.y + x.z + x.w;
        float s2 = x.x*x.x + x.y*x.y + x.z*x.z + x.w*x.w;
        #pragma unroll
        for (int off = 32; off > 0; off >>= 1) {
            s  += __shfl_down(s,  off, 64);
            s2 += __shfl_down(s2, off, 64);
        }
        s  = __shfl(s,  0, 64);
        s2 = __shfl(s2, 0, 64);
        float mu = s * (1.f / 256.f);
        float rs = rsqrtf(s2 * (1.f / 256.f) - mu * mu + 1e-5f);
        u32 lo = pkbf((x.x - mu) * rs * gg.x + bb.x, (x.y - mu) * rs * gg.y + bb.y);
        u32 hi = pkbf((x.z - mu) * rs * gg.z + bb.z, (x.w - mu) * rs * gg.w + bb.w);
        *(uint2*)(x2b + (size_t)(n0 + r) * 256 + l * 4) = make_uint2(lo, hi);
    }
}

// ------------- MFMA flash attention, in-register softmax (T12) -------------
// (R2-verbatim — best measured variant)
__global__ __launch_bounds__(256, 4) void attn_k(const u16* __restrict__ qb,
        const u16* __restrict__ kfb, const u16* __restrict__ vfb,
        u16* __restrict__ attn) {
    const int id = blockIdx.x;                 // 1024 blocks
    const int bh   = (id & 7) * 4 + (id >> 8); // xcd*4 + group
    const int tile = (id >> 3) & 31;           // 64-q tile within bh
    const int b = bh >> 3, h = bh & 7;
    const int tid = threadIdx.x, w = tid >> 6, l = tid & 63;
    const int qw = w & 1, kw = w >> 1;
    const int lq = l & 31, hi = l >> 5;
    const size_t btok = (size_t)b * TS;
    const int q0 = tile * 64 + qw * 32;

    __shared__ float mrg[2304];                // 2 x 64 lanes x 18 f32

    // Q frags: B-op [col=q=l&31][k=d=(l>>5)*8..+8], pre-scaled by QSCALE
    const u16* qrow = qb + (btok + q0 + lq) * 256 + h * 32 + hi * 8;
    bf16x8 qf0 = *(const bf16x8*)qrow;         // d 0..16
    bf16x8 qf1 = *(const bf16x8*)(qrow + 16);  // d 16..32

    f32x16 zf, o;
    #pragma unroll
    for (int r = 0; r < 16; r++) { zf[r] = 0.f; o[r] = 0.f; }
    float ps = 0.f;

    // fragment streams: 1024 u16 per 32-kv tile, lane l owns bytes l*16..+16
    const u16* kp = kfb + ((size_t)bh * 64 + kw * 32) * 1024 + l * 8;
    const u16* vp = vfb + ((size_t)bh * 64 + kw * 32) * 1024 + l * 8;
    bf16x8 k0 = *(const bf16x8*)kp;
    bf16x8 k1 = *(const bf16x8*)(kp + 512);
    bf16x8 v0 = *(const bf16x8*)vp;
    bf16x8 v1 = *(const bf16x8*)(vp + 512);

    #pragma unroll 2
    for (int it = 0; it < 32; ++it) {
        kp += 1024; vp += 1024;
        // prefetch next tile (last iter reads 1 tile past end -> in-ws, unused)
        bf16x8 nk0 = *(const bf16x8*)kp;
        bf16x8 nk1 = *(const bf16x8*)(kp + 512);
        bf16x8 nv0 = *(const bf16x8*)vp;
        bf16x8 nv1 = *(const bf16x8*)(vp + 512);
        // S[kv][q] (col=q): two chained MFMAs cover d=32
        f32x16 p = __builtin_amdgcn_mfma_f32_32x32x16_bf16(k0, qf0, zf, 0, 0, 0);
        p = __builtin_amdgcn_mfma_f32_32x32x16_bf16(k1, qf1, p, 0, 0, 0);
        float e[16];
        #pragma unroll
        for (int r = 0; r < 16; r++) e[r] = EXP2(p[r]);
        ps += ((e[0]+e[1]) + (e[2]+e[3])) + ((e[4]+e[5]) + (e[6]+e[7]))
            + ((e[8]+e[9]) + (e[10]+e[11])) + ((e[12]+e[13]) + (e[14]+e[15]));
        // pack: a[j] = bf16(e[2j]) | bf16(e[2j+1])<<16  (kv-consecutive pairs)
        u32 a[8];
        #pragma unroll
        for (int j = 0; j < 8; j++)
            asm("v_cvt_pk_bf16_f32 %0, %1, %2"
                : "=v"(a[j]) : "v"(e[2*j]), "v"(e[2*j+1]));
        // redistribute across lane halves: (w0,w2)=swap(a0,a2) etc (T12)
        asm("v_permlane32_swap_b32 %0, %1" : "+v"(a[0]), "+v"(a[2]));
        asm("v_permlane32_swap_b32 %0, %1" : "+v"(a[1]), "+v"(a[3]));
        asm("v_permlane32_swap_b32 %0, %1" : "+v"(a[4]), "+v"(a[6]));
        asm("v_permlane32_swap_b32 %0, %1" : "+v"(a[5]), "+v"(a[7]));
        u32v4 t0 = {a[0], a[1], a[2], a[3]};   // P^T[q][kv0+hi*8 .. +8]
        u32v4 t1 = {a[4], a[5], a[6], a[7]};   // P^T[q][kv0+16+hi*8 .. +8]
        bf16x8 pf0 = __builtin_bit_cast(bf16x8, t0);
        bf16x8 pf1 = __builtin_bit_cast(bf16x8, t1);
        // O^T[d][q] += V^T * P^T
        o = __builtin_amdgcn_mfma_f32_32x32x16_bf16(v0, pf0, o, 0, 0, 0);
        o = __builtin_amdgcn_mfma_f32_32x32x16_bf16(v1, pf1, o, 0, 0, 0);
        k0 = nk0; k1 = nk1; v0 = nv0; v1 = nv1;
    }
    // lane l and l+32 (same q) cover complementary kv rows -> full half-sum
    ps += __shfl_xor(ps, 32, 64);

    // merge the two kv halves: kw=1 dumps (o, ps); kw=0 adds + stores
    if (kw == 1) {
        float* d = mrg + (qw * 64 + l) * 18;
        #pragma unroll
        for (int r = 0; r < 16; r++) d[r] = o[r];
        d[16] = ps;
    }
    __syncthreads();
    if (kw == 0) {
        const float* d = mrg + (qw * 64 + l) * 18;
        #pragma unroll
        for (int r = 0; r < 16; r++) o[r] += d[r];
        ps += d[16];
        float inv = 1.f / ps;
        // o reg r -> d = 8*(r>>2) + 4*hi + (r&3); q = lq
        int tok = (int)btok + q0 + lq;
        u16* orow = attn + (size_t)tok * 256 + h * 32 + hi * 4;
        #pragma unroll
        for (int g = 0; g < 4; g++)
            *(uint2*)(orow + g * 8) = make_uint2(
                pkbf(o[4*g]*inv, o[4*g+1]*inv), pkbf(o[4*g+2]*inv, o[4*g+3]*inv));
    }
}

extern "C" void kernel_launch(void* const* d_in, const int* in_sizes, int n_in,
                              void* d_out, int out_size, void* d_ws, size_t ws_size,
                              hipStream_t stream) {
    const float* src  = (const float*)d_in[0];
    const float* w_in = (const float*)d_in[1];
    const float* w_out= (const float*)d_in[2];
    const float* w1   = (const float*)d_in[3];
    const float* b1   = (const float*)d_in[4];
    const float* w2   = (const float*)d_in[5];
    const float* b2   = (const float*)d_in[6];
    const float* g1   = (const float*)d_in[7];
    const float* be1  = (const float*)d_in[8];
    const float* g2   = (const float*)d_in[9];
    const float* be2  = (const float*)d_in[10];
    float* out = (float*)d_out;

    u16* xb    = (u16*)d_ws;                       // [0, 4MB)    8192 x 256
    u16* qb    = xb + (size_t)NTOK * 256;          // [4, 8MB)    8192 x 256 Q
    u16* kfbuf = qb + (size_t)NTOK * 256;          // [8, 12MB)   K frags
    u16* vfbuf = kfbuf + (size_t)32 * 64 * 1024;   // [12, 16MB)  V frags
    u16* attnb = xb;                               // reuse (xb dead after G2)
    u16* h1b   = (u16*)d_ws;                       // 8192*1024 (after attn GEMMs)
    u16* x2b   = (u16*)((char*)d_ws + (size_t)NTOK * 1024 * 2);
    u16* wib   = x2b + (size_t)NTOK * 256;
    u16* wob   = wib + 768 * 256;
    u16* w1b   = wob + 256 * 256;
    u16* w2b   = w1b + 1024 * 256;

    // 1. weights -> bf16  +  xb = LN1(src) -> bf16   (one kernel)
    prep<<<768 + NTOK / 4, 256, 0, stream>>>(
        w_in, wib, w_out, wob, w1, w1b, w2, w2b, src, xb, g1, be1);
    // 2. qb = Q (scaled), kfbuf/vfbuf = K,V fragment-ordered  (= xb @ w_in^T)
    mgemm<256, 128, 0><<<dim3(6, 64), 256, 0, stream>>>(
        xb, wib, (const float*)kfbuf, (const float*)vfbuf, nullptr, qb, 768);
    // 3. attnb = flash-attention(qb, kfbuf, vfbuf)
    attn_k<<<dim3(1024), 256, 0, stream>>>(qb, kfbuf, vfbuf, attnb);
    // 4. out = src + attnb @ w_out^T (fp32)  +  x2b = LN2(out)   (fused)
    g4ln<<<256, 512, 0, stream>>>(attnb, wob, src, out, x2b, g2, be2);
    // 5. h1b = relu(x2b @ w1^T + b1) -> bf16
    mgemm<256, 128, 2><<<dim3(8, 64), 256, 0, stream>>>(
        x2b, w1b, b1, nullptr, nullptr, h1b, 1024);
    // 6. out = out + h1b @ w2^T + b2 (fp32)
    mgemm<1024, 64, 3><<<dim3(4, 128), 256, 0, stream>>>(
        h1b, w2b, b2, out, out, nullptr, 256);
}

// Round 10
// 157.303 us; speedup vs baseline: 1.0899x; 1.0144x over previous
//
#include <hip/hip_runtime.h>
#include <hip/hip_bf16.h>
#include <math.h>

typedef unsigned short u16;
typedef unsigned int   u32;
using bf16x8 = __attribute__((ext_vector_type(8))) short;   // 8 bf16 (4 VGPRs)
using f32x4  = __attribute__((ext_vector_type(4))) float;   // MFMA C/D frag
using f32x16 = __attribute__((ext_vector_type(16))) float;  // 32x32 C/D frag
using u32v4  = __attribute__((ext_vector_type(4))) u32;

#define TE 256
#define TH 8
#define TS 2048
#define TB 4
#define NTOK 8192
// (1/sqrt(32)) * log2(e): folded into Q so softmax is pure exp2
#define QSCALE 0.2550120651552454f
#define EXP2(x) __builtin_amdgcn_exp2f(x)

__device__ __forceinline__ void async16(const u16* g, u16* l) {
    __builtin_amdgcn_global_load_lds(
        (const __attribute__((address_space(1))) u32*)g,
        (__attribute__((address_space(3))) u32*)l, 16, 0, 0);
}
// pack 2 floats -> 2 bf16 (round-half-up): 2 adds + v_perm
__device__ __forceinline__ u32 pkbf(float a, float b) {
    u32 ua = __float_as_uint(a) + 0x8000u;
    u32 ub = __float_as_uint(b) + 0x8000u;
    return __builtin_amdgcn_perm(ub, ua, 0x07060302u);  // [ub.b3 ub.b2 ua.b3 ua.b2]
}
__device__ __forceinline__ u16 bf1(float a) {
    return (u16)((__float_as_uint(a) + 0x8000u) >> 16);
}

// ---------------- LayerNorm body: one wave per row, bf16 output ------------
__device__ __forceinline__ void ln_body(const float* __restrict__ in,
        u16* __restrict__ out, const float* __restrict__ gamma,
        const float* __restrict__ beta, int rowblk) {
    int row  = rowblk * 4 + (threadIdx.x >> 6);
    int lane = threadIdx.x & 63;
    float4 v = ((const float4*)(in + (size_t)row * TE))[lane];
    float s  = v.x + v.y + v.z + v.w;
    float s2 = v.x*v.x + v.y*v.y + v.z*v.z + v.w*v.w;
    #pragma unroll
    for (int off = 32; off > 0; off >>= 1) {
        s  += __shfl_down(s,  off, 64);
        s2 += __shfl_down(s2, off, 64);
    }
    s  = __shfl(s,  0, 64);
    s2 = __shfl(s2, 0, 64);
    float mu = s * (1.f / TE);
    float rs = rsqrtf(s2 * (1.f / TE) - mu * mu + 1e-5f);
    float4 g = ((const float4*)gamma)[lane];
    float4 b = ((const float4*)beta )[lane];
    u32 lo = pkbf((v.x - mu) * rs * g.x + b.x, (v.y - mu) * rs * g.y + b.y);
    u32 hi = pkbf((v.z - mu) * rs * g.z + b.z, (v.w - mu) * rs * g.w + b.w);
    ((uint2*)(out + (size_t)row * TE))[lane] = make_uint2(lo, hi);
}

// ---- prep: weight fp32->bf16 conversion (768 blocks) + LN1 (2048 blocks) ---
__global__ __launch_bounds__(256) void prep(const float* __restrict__ s0, u16* d0,
        const float* __restrict__ s1, u16* d1, const float* __restrict__ s2, u16* d2,
        const float* __restrict__ s3, u16* d3, const float* __restrict__ src,
        u16* __restrict__ xb, const float* __restrict__ g1,
        const float* __restrict__ be1) {
    if (blockIdx.x < 768) {
        int i = (blockIdx.x * 256 + threadIdx.x) * 4;
        const float* s; u16* d;
        if      (i < 196608) { s = s0; d = d0; }
        else if (i < 262144) { s = s1; d = d1; i -= 196608; }
        else if (i < 524288) { s = s2; d = d2; i -= 262144; }
        else                 { s = s3; d = d3; i -= 524288; }
        float4 v = *(const float4*)(s + i);
        *(uint2*)(d + i) = make_uint2(pkbf(v.x, v.y), pkbf(v.z, v.w));
    } else {
        ln_body(src, xb, g1, be1, blockIdx.x - 768);
    }
}

// ------------------- MFMA GEMM: C[N,M] = A[N,K] @ W[M,K]^T -----------------
// R2-proven structure: BK=64 staged as two 32-halves per barrier pair.
// BM=BN=128: 4 waves x (64tok x 64feat). BM=BN=64: 4 waves x (32tok x 32feat)
// Operands swapped (D rows=feat, cols=tok) -> lane holds 4 consecutive feats.
// EPI: 0=QKV: feat<256 -> Q bf16 [tok][256] (qscaled); 256..511 -> K frag-
// ordered [bh][tile][frag][hi][lq][8] (Kf = bias); >=512 -> V frag-ordered
// same layout (Vf = R).  2=bf16 relu(acc+bias); 3=fp32 acc+bias+residual.
template<int K, int BM, int EPI>
__global__ __launch_bounds__(256) void mgemm(const u16* __restrict__ A,
        const u16* __restrict__ W, const float* __restrict__ bias,
        const float* __restrict__ R, float* __restrict__ Cf,
        u16* __restrict__ Cb, int M) {
    constexpr int BN = BM;                       // square tiles
    __shared__ u16 Al[2][BM * 32];
    __shared__ u16 Wl[2][BN * 32];
    const int tid = threadIdx.x, w = tid >> 6, l = tid & 63;
    const int n0 = blockIdx.y * BM;              // token base
    const int m0 = blockIdx.x * BN;              // feat base
    constexpr int NT = (BM == 128) ? 4 : 2;      // tok frags / wave
    constexpr int NF = (BM == 128) ? 4 : 2;      // feat frags / wave
    const int tw = (w & 1) * NT * 16;
    const int fw = (w >> 1) * NF * 16;
    const int fr = l & 15, fq = l >> 4;
    const int sr = l >> 2, sc = (l & 3) * 8;
    f32x4 acc[NT][NF];
    #pragma unroll
    for (int t = 0; t < NT; t++)
        #pragma unroll
        for (int f = 0; f < NF; f++)
            #pragma unroll
            for (int r = 0; r < 4; r++) acc[t][f][r] = 0.f;

    for (int k0 = 0; k0 < K; k0 += 64) {
        __syncthreads();
        #pragma unroll
        for (int hh = 0; hh < 2; hh++) {
            const int kc = k0 + hh * 32;
            if (BM == 128) {
                #pragma unroll
                for (int c = 0; c < 2; c++) {
                    int rr = (w * 2 + c) * 16 + sr;
                    async16(A + (size_t)(n0 + rr) * K + kc + sc, &Al[hh][(w * 2 + c) * 512]);
                    async16(W + (size_t)(m0 + rr) * K + kc + sc, &Wl[hh][(w * 2 + c) * 512]);
                }
            } else {
                int rr = w * 16 + sr;
                async16(A + (size_t)(n0 + rr) * K + kc + sc, &Al[hh][w * 512]);
                async16(W + (size_t)(m0 + rr) * K + kc + sc, &Wl[hh][w * 512]);
            }
        }
        __syncthreads();
        #pragma unroll
        for (int hh = 0; hh < 2; hh++) {
            bf16x8 af[NT], wf[NF];
            #pragma unroll
            for (int t = 0; t < NT; t++)
                af[t] = *(const bf16x8*)&Al[hh][(tw + t * 16 + fr) * 32 + fq * 8];
            #pragma unroll
            for (int f = 0; f < NF; f++)
                wf[f] = *(const bf16x8*)&Wl[hh][(fw + f * 16 + fr) * 32 + fq * 8];
            #pragma unroll
            for (int t = 0; t < NT; t++)
                #pragma unroll
                for (int f = 0; f < NF; f++)
                    acc[t][f] = __builtin_amdgcn_mfma_f32_16x16x32_bf16(
                        wf[f], af[t], acc[t][f], 0, 0, 0);   // D rows=feat, cols=tok
        }
    }
    // epilogue: lane holds (tok = n0+tw+t*16+fr, feats fb..fb+3)
    #pragma unroll
    for (int t = 0; t < NT; t++) {
        const int tok = n0 + tw + t * 16 + fr;
        #pragma unroll
        for (int f = 0; f < NF; f++) {
            const int fb = m0 + fw + f * 16 + fq * 4;
            f32x4 v = acc[t][f];
            if (EPI == 0) {
                if (fb < 256) {
                    *(uint2*)(Cb + (size_t)tok * 256 + fb) = make_uint2(
                        pkbf(v[0]*QSCALE, v[1]*QSCALE), pkbf(v[2]*QSCALE, v[3]*QSCALE));
                } else if (fb < 512) {
                    // K fragment-ordered: [bh][tile][frag][hi][lq][8]
                    const int hh = (fb - 256) >> 5, dd = (fb - 256) & 31;
                    const int bh = (tok >> 11) * 8 + hh;
                    const int kv = tok & 2047, tile = kv >> 5, lq = kv & 31;
                    const int fg = dd >> 4, hg = (dd >> 3) & 1, j = dd & 7;
                    u16* kp = (u16*)bias +
                        (((((size_t)bh * 64 + tile) * 2 + fg) * 2 + hg) * 32 + lq) * 8 + j;
                    *(uint2*)kp = make_uint2(pkbf(v[0], v[1]), pkbf(v[2], v[3]));
                } else {
                    // V fragment-ordered: row = d, k-chunk = kv-within-tile
                    const int hh = (fb - 512) >> 5, dd = (fb - 512) & 31;
                    const int bh = (tok >> 11) * 8 + hh;
                    const int kv = tok & 2047, tile = kv >> 5, kvr = kv & 31;
                    const int fg = kvr >> 4, hg = (kvr >> 3) & 1, j = kvr & 7;
                    u16* vp = (u16*)R +
                        ((((size_t)bh * 64 + tile) * 2 + fg) * 2 + hg) * 256 +
                        (size_t)dd * 8 + j;
                    vp[0]  = bf1(v[0]);
                    vp[8]  = bf1(v[1]);
                    vp[16] = bf1(v[2]);
                    vp[24] = bf1(v[3]);
                }
            } else if (EPI == 2) {
                float4 b4 = *(const float4*)(bias + fb);
                *(uint2*)(Cb + (size_t)tok * M + fb) = make_uint2(
                    pkbf(fmaxf(v[0]+b4.x, 0.f), fmaxf(v[1]+b4.y, 0.f)),
                    pkbf(fmaxf(v[2]+b4.z, 0.f), fmaxf(v[3]+b4.w, 0.f)));
            } else {
                float4 b4 = *(const float4*)(bias + fb);
                float4 r4 = *(const float4*)(R + (size_t)tok * M + fb);
                *(float4*)(Cf + (size_t)tok * M + fb) = make_float4(
                    v[0]+b4.x+r4.x, v[1]+b4.y+r4.y, v[2]+b4.z+r4.z, v[3]+b4.w+r4.w);
            }
        }
    }
}

// ---- g4ln: out = src + attnb @ w_out^T, then x2b = LN2(out) (fused) -------
// Block = 32 tokens x all 256 feats (K=256), 8 waves: tg=w&1 (16 tok),
// fg=w>>1 (64 feats).  Epilogue owns complete rows -> LN computed in-block
// from an LDS fp32 tile (row pad 260 breaks bank aliasing).  Saves the
// separate LN2 kernel + its 12 MB round-trip.
__global__ __launch_bounds__(512) void g4ln(const u16* __restrict__ A,
        const u16* __restrict__ W, const float* __restrict__ src,
        float* __restrict__ out, u16* __restrict__ x2b,
        const float* __restrict__ g2, const float* __restrict__ be2) {
    __shared__ __align__(16) char smem[36864];
    u16* Al = (u16*)smem;                  // [2][32*32]
    u16* Wl = (u16*)(smem + 4096);         // [2][256*32]
    const int tid = threadIdx.x, w = tid >> 6, l = tid & 63;
    const int tg = w & 1, fg = w >> 1;
    const int fr = l & 15, fq = l >> 4;
    const int sr = l >> 2, sc = (l & 3) * 8;
    const int n0 = blockIdx.x * 32;
    f32x4 acc[4];
    #pragma unroll
    for (int f = 0; f < 4; f++)
        #pragma unroll
        for (int r = 0; r < 4; r++) acc[f][r] = 0.f;

    auto stage = [&](int st, int buf) {
        const int kc = st * 32;
        const int rr = w * 16 + sr;
        async16(W + (size_t)rr * 256 + kc + sc, &Wl[buf * 8192 + w * 512]);
        async16(W + (size_t)(rr + 128) * 256 + kc + sc, &Wl[buf * 8192 + 4096 + w * 512]);
        if (w < 2) async16(A + (size_t)(n0 + rr) * 256 + kc + sc, &Al[buf * 1024 + w * 512]);
    };

    stage(0, 0);
    __syncthreads();
    #pragma unroll 2
    for (int st = 0; st < 8; ++st) {
        const int buf = st & 1;
        if (st + 1 < 8) stage(st + 1, buf ^ 1);
        bf16x8 af = *(const bf16x8*)&Al[buf * 1024 + (tg * 16 + fr) * 32 + fq * 8];
        bf16x8 wf[4];
        #pragma unroll
        for (int f = 0; f < 4; f++)
            wf[f] = *(const bf16x8*)&Wl[buf * 8192 + (fg * 64 + f * 16 + fr) * 32 + fq * 8];
        #pragma unroll
        for (int f = 0; f < 4; f++)
            acc[f] = __builtin_amdgcn_mfma_f32_16x16x32_bf16(wf[f], af, acc[f], 0, 0, 0);
        __syncthreads();
    }
    // epilogue: residual add, write out, stash rows in LDS, then LN in-block
    float* T = (float*)smem;               // [32][260] f32 (33280 B <= 36864)
    const int tokl = tg * 16 + fr;
    const int tok  = n0 + tokl;
    #pragma unroll
    for (int f = 0; f < 4; ++f) {
        const int fb = fg * 64 + f * 16 + fq * 4;
        float4 s4 = *(const float4*)(src + (size_t)tok * 256 + fb);
        f32x4 v = acc[f];
        float4 o4 = make_float4(v[0]+s4.x, v[1]+s4.y, v[2]+s4.z, v[3]+s4.w);
        *(float4*)(out + (size_t)tok * 256 + fb) = o4;
        *(float4*)&T[tokl * 260 + fb] = o4;
    }
    __syncthreads();
    float4 gg = ((const float4*)g2)[l];
    float4 bb = ((const float4*)be2)[l];
    #pragma unroll
    for (int rr = 0; rr < 4; ++rr) {
        const int r = w * 4 + rr;
        float4 x = *(const float4*)&T[r * 260 + l * 4];
        float s  = x.x + x.y + x.z + x.w;
        float s2 = x.x*x.x + x.y*x.y + x.z*x.z + x.w*x.w;
        #pragma unroll
        for (int off = 32; off > 0; off >>= 1) {
            s  += __shfl_down(s,  off, 64);
            s2 += __shfl_down(s2, off, 64);
        }
        s  = __shfl(s,  0, 64);
        s2 = __shfl(s2, 0, 64);
        float mu = s * (1.f / 256.f);
        float rs = rsqrtf(s2 * (1.f / 256.f) - mu * mu + 1e-5f);
        u32 lo = pkbf((x.x - mu) * rs * gg.x + bb.x, (x.y - mu) * rs * gg.y + bb.y);
        u32 hi = pkbf((x.z - mu) * rs * gg.z + bb.z, (x.w - mu) * rs * gg.w + bb.w);
        *(uint2*)(x2b + (size_t)(n0 + r) * 256 + l * 4) = make_uint2(lo, hi);
    }
}

// ------------- MFMA flash attention, in-register softmax (T12) -------------
// 32x32x16 MFMAs, swapped QK^T (mfma(K,Q)): lane (col=q=l&31) holds 16 P
// values.  P -> bf16 PV-fragment fully in-register (cvt_pk + permlane32).
// K/V pre-fragmented in global (QKV-GEMM epilogue) -> 1KB coalesced wave
// loads.  DEPTH-2 register prefetch: loads for tile i+2 are issued before
// computing tile i (~360cy of cover > ~250cy L2 latency; the old 1-deep
// ring exposed ~70-100cy of vmcnt stall every iteration).  Four named
// K/V register sets (a/b live, c/d in flight) -- no runtime-indexed arrays
// (rule #20).  kv-split 2: waves (qw=w&1, kw=w>>1); partials merge by
// addition in LDS.  Block swizzle pins each (b,h) to one XCD.
__global__ __launch_bounds__(256, 4) void attn_k(const u16* __restrict__ qb,
        const u16* __restrict__ kfb, const u16* __restrict__ vfb,
        u16* __restrict__ attn) {
    const int id = blockIdx.x;                 // 1024 blocks
    const int bh   = (id & 7) * 4 + (id >> 8); // xcd*4 + group
    const int tile = (id >> 3) & 31;           // 64-q tile within bh
    const int b = bh >> 3, h = bh & 7;
    const int tid = threadIdx.x, w = tid >> 6, l = tid & 63;
    const int qw = w & 1, kw = w >> 1;
    const int lq = l & 31, hi = l >> 5;
    const size_t btok = (size_t)b * TS;
    const int q0 = tile * 64 + qw * 32;

    __shared__ float mrg[2304];                // 2 x 64 lanes x 18 f32

    // Q frags: B-op [col=q=l&31][k=d=(l>>5)*8..+8], pre-scaled by QSCALE
    const u16* qrow = qb + (btok + q0 + lq) * 256 + h * 32 + hi * 8;
    bf16x8 qf0 = *(const bf16x8*)qrow;         // d 0..16
    bf16x8 qf1 = *(const bf16x8*)(qrow + 16);  // d 16..32

    f32x16 zf, o;
    #pragma unroll
    for (int r = 0; r < 16; r++) { zf[r] = 0.f; o[r] = 0.f; }
    float ps = 0.f;

    // fragment streams: 1024 u16 per 32-kv tile, lane l owns bytes l*16..+16
    const u16* kp = kfb + ((size_t)bh * 64 + kw * 32) * 1024 + l * 8;
    const u16* vp = vfb + ((size_t)bh * 64 + kw * 32) * 1024 + l * 8;

    // per-32kv-tile compute: QK^T -> exp2 -> pack -> permlane -> PV
    auto body = [&](bf16x8 k0, bf16x8 k1, bf16x8 v0, bf16x8 v1) {
        f32x16 p = __builtin_amdgcn_mfma_f32_32x32x16_bf16(k0, qf0, zf, 0, 0, 0);
        p = __builtin_amdgcn_mfma_f32_32x32x16_bf16(k1, qf1, p, 0, 0, 0);
        float e[16];
        #pragma unroll
        for (int r = 0; r < 16; r++) e[r] = EXP2(p[r]);
        ps += ((e[0]+e[1]) + (e[2]+e[3])) + ((e[4]+e[5]) + (e[6]+e[7]))
            + ((e[8]+e[9]) + (e[10]+e[11])) + ((e[12]+e[13]) + (e[14]+e[15]));
        u32 a[8];
        #pragma unroll
        for (int j = 0; j < 8; j++)
            asm("v_cvt_pk_bf16_f32 %0, %1, %2"
                : "=v"(a[j]) : "v"(e[2*j]), "v"(e[2*j+1]));
        asm("v_permlane32_swap_b32 %0, %1" : "+v"(a[0]), "+v"(a[2]));
        asm("v_permlane32_swap_b32 %0, %1" : "+v"(a[1]), "+v"(a[3]));
        asm("v_permlane32_swap_b32 %0, %1" : "+v"(a[4]), "+v"(a[6]));
        asm("v_permlane32_swap_b32 %0, %1" : "+v"(a[5]), "+v"(a[7]));
        u32v4 t0 = {a[0], a[1], a[2], a[3]};   // P^T[q][kv0+hi*8 .. +8]
        u32v4 t1 = {a[4], a[5], a[6], a[7]};   // P^T[q][kv0+16+hi*8 .. +8]
        bf16x8 pf0 = __builtin_bit_cast(bf16x8, t0);
        bf16x8 pf1 = __builtin_bit_cast(bf16x8, t1);
        o = __builtin_amdgcn_mfma_f32_32x32x16_bf16(v0, pf0, o, 0, 0, 0);
        o = __builtin_amdgcn_mfma_f32_32x32x16_bf16(v1, pf1, o, 0, 0, 0);
    };

    // depth-2 pipeline: a/b = tiles i, i+1 (live); c/d = tiles i+2, i+3
    bf16x8 ak0 = *(const bf16x8*)(kp);
    bf16x8 ak1 = *(const bf16x8*)(kp + 512);
    bf16x8 av0 = *(const bf16x8*)(vp);
    bf16x8 av1 = *(const bf16x8*)(vp + 512);
    bf16x8 bk0 = *(const bf16x8*)(kp + 1024);
    bf16x8 bk1 = *(const bf16x8*)(kp + 1536);
    bf16x8 bv0 = *(const bf16x8*)(vp + 1024);
    bf16x8 bv1 = *(const bf16x8*)(vp + 1536);
    u32 off = 2048;
    for (int it = 0; it < 32; it += 2) {
        // issue tile i+2 (last pair reads past end -> in-ws, unused)
        bf16x8 ck0 = *(const bf16x8*)(kp + off);
        bf16x8 ck1 = *(const bf16x8*)(kp + off + 512);
        bf16x8 cv0 = *(const bf16x8*)(vp + off);
        bf16x8 cv1 = *(const bf16x8*)(vp + off + 512);
        body(ak0, ak1, av0, av1);
        // issue tile i+3
        bf16x8 dk0 = *(const bf16x8*)(kp + off + 1024);
        bf16x8 dk1 = *(const bf16x8*)(kp + off + 1536);
        bf16x8 dv0 = *(const bf16x8*)(vp + off + 1024);
        bf16x8 dv1 = *(const bf16x8*)(vp + off + 1536);
        body(bk0, bk1, bv0, bv1);
        ak0 = ck0; ak1 = ck1; av0 = cv0; av1 = cv1;
        bk0 = dk0; bk1 = dk1; bv0 = dv0; bv1 = dv1;
        off += 2048;
    }
    // lane l and l+32 (same q) cover complementary kv rows -> full half-sum
    ps += __shfl_xor(ps, 32, 64);

    // merge the two kv halves: kw=1 dumps (o, ps); kw=0 adds + stores
    if (kw == 1) {
        float* d = mrg + (qw * 64 + l) * 18;
        #pragma unroll
        for (int r = 0; r < 16; r++) d[r] = o[r];
        d[16] = ps;
    }
    __syncthreads();
    if (kw == 0) {
        const float* d = mrg + (qw * 64 + l) * 18;
        #pragma unroll
        for (int r = 0; r < 16; r++) o[r] += d[r];
        ps += d[16];
        float inv = 1.f / ps;
        // o reg r -> d = 8*(r>>2) + 4*hi + (r&3); q = lq
        int tok = (int)btok + q0 + lq;
        u16* orow = attn + (size_t)tok * 256 + h * 32 + hi * 4;
        #pragma unroll
        for (int g = 0; g < 4; g++)
            *(uint2*)(orow + g * 8) = make_uint2(
                pkbf(o[4*g]*inv, o[4*g+1]*inv), pkbf(o[4*g+2]*inv, o[4*g+3]*inv));
    }
}

extern "C" void kernel_launch(void* const* d_in, const int* in_sizes, int n_in,
                              void* d_out, int out_size, void* d_ws, size_t ws_size,
                              hipStream_t stream) {
    const float* src  = (const float*)d_in[0];
    const float* w_in = (const float*)d_in[1];
    const float* w_out= (const float*)d_in[2];
    const float* w1   = (const float*)d_in[3];
    const float* b1   = (const float*)d_in[4];
    const float* w2   = (const float*)d_in[5];
    const float* b2   = (const float*)d_in[6];
    const float* g1   = (const float*)d_in[7];
    const float* be1  = (const float*)d_in[8];
    const float* g2   = (const float*)d_in[9];
    const float* be2  = (const float*)d_in[10];
    float* out = (float*)d_out;

    u16* xb    = (u16*)d_ws;                       // [0, 4MB)    8192 x 256
    u16* qb    = xb + (size_t)NTOK * 256;          // [4, 8MB)    8192 x 256 Q
    u16* kfbuf = qb + (size_t)NTOK * 256;          // [8, 12MB)   K frags
    u16* vfbuf = kfbuf + (size_t)32 * 64 * 1024;   // [12, 16MB)  V frags
    u16* attnb = xb;                               // reuse (xb dead after G2)
    u16* h1b   = (u16*)d_ws;                       // 8192*1024 (after attn GEMMs)
    u16* x2b   = (u16*)((char*)d_ws + (size_t)NTOK * 1024 * 2);
    u16* wib   = x2b + (size_t)NTOK * 256;
    u16* wob   = wib + 768 * 256;
    u16* w1b   = wob + 256 * 256;
    u16* w2b   = w1b + 1024 * 256;

    // 1. weights -> bf16  +  xb = LN1(src) -> bf16   (one kernel)
    prep<<<768 + NTOK / 4, 256, 0, stream>>>(
        w_in, wib, w_out, wob, w1, w1b, w2, w2b, src, xb, g1, be1);
    // 2. qb = Q (scaled), kfbuf/vfbuf = K,V fragment-ordered  (= xb @ w_in^T)
    mgemm<256, 128, 0><<<dim3(6, 64), 256, 0, stream>>>(
        xb, wib, (const float*)kfbuf, (const float*)vfbuf, nullptr, qb, 768);
    // 3. attnb = flash-attention(qb, kfbuf, vfbuf)
    attn_k<<<dim3(1024), 256, 0, stream>>>(qb, kfbuf, vfbuf, attnb);
    // 4. out = src + attnb @ w_out^T (fp32)  +  x2b = LN2(out)   (fused)
    g4ln<<<256, 512, 0, stream>>>(attnb, wob, src, out, x2b, g2, be2);
    // 5. h1b = relu(x2b @ w1^T + b1) -> bf16
    mgemm<256, 128, 2><<<dim3(8, 64), 256, 0, stream>>>(
        x2b, w1b, b1, nullptr, nullptr, h1b, 1024);
    // 6. out = out + h1b @ w2^T + b2 (fp32)
    mgemm<1024, 64, 3><<<dim3(4, 128), 256, 0, stream>>>(
        h1b, w2b, b2, out, out, nullptr, 256);
}